// Round 12
// baseline (368.911 us; speedup 1.0000x reference)
//
#include <hip/hip_runtime.h>
#include <hip/hip_fp16.h>

#define NN 100000
#define NE 1600000
#define FIN 128
#define HD 64
#define CO 40
#define NG 2048
#define NBUK 782          // ceil(NN/128)
#define BCAP 3072         // tmp bucket capacity (mean 2046, >20 sigma margin)
#define PCAP 3584         // padded ssrc capacity (cnt + 128*7 worst-case pad)
#define CHUNK 4096        // edges per scatter block
#define NSCAT ((NE + CHUNK - 1) / CHUNK)   // 391

// ---------------- init padded cursors ----------------
__global__ __launch_bounds__(256) void init_kernel(int* __restrict__ ccur) {
    int b = blockIdx.x * 256 + threadIdx.x;
    if (b < NBUK) ccur[b * 16] = b * BCAP;
}

// =====================================================================
// Two-phase binned scatter (unchanged from R11): block-private ranges
// mean every tmp line is assembled by one workgroup.
// =====================================================================
__global__ __launch_bounds__(256) void scatter_binned(const int* __restrict__ src,
                                                      const int* __restrict__ dst,
                                                      int* __restrict__ ccur,
                                                      unsigned int* __restrict__ tmp) {
    __shared__ int hist[NBUK];
    __shared__ int gbase[NBUK];
    int tid = threadIdx.x;
    int e0 = blockIdx.x * CHUNK;
    int e1 = e0 + CHUNK; if (e1 > NE) e1 = NE;
    for (int i = tid; i < NBUK; i += 256) hist[i] = 0;
    __syncthreads();
    for (int e = e0 + tid; e < e1; e += 256) atomicAdd(&hist[dst[e] >> 7], 1);
    __syncthreads();
    for (int b = tid; b < NBUK; b += 256) {
        int c = hist[b];
        gbase[b] = (c > 0) ? atomicAdd(&ccur[b * 16], c) : 0;
    }
    __syncthreads();
    for (int b = tid; b < NBUK; b += 256) hist[b] = 0;
    __syncthreads();
    for (int e = e0 + tid; e < e1; e += 256) {
        int d = dst[e];
        int s = src[e];
        int b = d >> 7;
        int p = atomicAdd(&hist[b], 1);
        tmp[gbase[b] + p] = ((unsigned int)(d & 127) << 17) | (unsigned int)s;
    }
}

// =====================================================================
// Per-bucket counting sort -> ssrc with per-node lists PADDED to a
// multiple of 8 using dummy src = NN (hws row NN is zeroed).
// degn stores the PADDED degree; di from the real degree.
// =====================================================================
__global__ __launch_bounds__(256) void bucket_sort(const int* __restrict__ ccur,
                                                   const unsigned int* __restrict__ tmp,
                                                   unsigned int* __restrict__ ssrc,
                                                   int* __restrict__ offs,
                                                   int* __restrict__ degn,
                                                   float* __restrict__ di) {
    __shared__ int lh[128];
    __shared__ int ls[128];
    __shared__ int lcur[128];
    __shared__ unsigned int lsorted[PCAP];
    int b = blockIdx.x;
    int tid = threadIdx.x;
    int base = b * BCAP;
    int cnt = ccur[b * 16] - base;
    if (tid < 128) lh[tid] = 0;
    __syncthreads();
    for (int i = tid; i < cnt; i += 256) {
        unsigned int u = tmp[base + i];
        atomicAdd(&lh[(u >> 17) & 127], 1);
    }
    __syncthreads();
    int pd = 0;
    if (tid < 128) { pd = (lh[tid] + 7) & ~7; ls[tid] = pd; }
    __syncthreads();
    for (int off = 1; off < 128; off <<= 1) {
        int v = 0;
        if (tid < 128 && tid >= off) v = ls[tid - off];
        __syncthreads();
        if (tid < 128) ls[tid] += v;
        __syncthreads();
    }
    if (tid < 128) {
        int pexcl = ls[tid] - pd;
        lcur[tid] = pexcl;
        int node = b * 128 + tid;
        if (node < NN) {
            offs[node] = b * PCAP + pexcl;
            degn[node] = pd;
            di[node] = rsqrtf((float)lh[tid] + 1.0f);
        }
    }
    __syncthreads();
    int total = ls[127];
    for (int i = tid; i < total; i += 256) lsorted[i] = (unsigned int)NN;  // dummy fill
    __syncthreads();
    for (int i = tid; i < cnt; i += 256) {
        unsigned int u = tmp[base + i];
        int dl = (u >> 17) & 127;
        int pos = atomicAdd(&lcur[dl], 1);
        lsorted[pos] = u & 0x1FFFFu;
    }
    __syncthreads();
    for (int i = tid; i < total; i += 256) ssrc[(size_t)b * PCAP + i] = lsorted[i];
}

// =====================================================================
// Tiled GEMM 1 with fused W_eff/b_eff: hws = half((x@(pre_w@c1_w) +
// pre_b@c1_w) * di).  Prologue stages c1_w in xS, computes wS + bS.
// Also zeroes the dummy row hws[NN].
// =====================================================================
__global__ __launch_bounds__(256) void gemm1_tiled(const float* __restrict__ x,
                                                   const float* __restrict__ pre_w,
                                                   const float* __restrict__ pre_b,
                                                   const float* __restrict__ c1w,
                                                   const float* __restrict__ di,
                                                   __half* __restrict__ hws) {
    __shared__ float wS[FIN * HD];   // 32 KB  W_eff [k][f]
    __shared__ float xS[64 * 64];    // 16 KB  (c1_w staging, then x K-half)
    __shared__ float bS[HD];
    int tid = threadIdx.x;
    // ---- prologue: W_eff = pre_w @ c1_w ; b_eff = pre_b @ c1_w ----
    for (int i = tid; i < HD * HD; i += 256) xS[i] = c1w[i];
    __syncthreads();
    for (int idx = tid; idx < FIN * HD; idx += 256) {
        int r = idx >> 6, c = idx & 63;
        float a = 0.0f;
#pragma unroll 8
        for (int j = 0; j < HD; j++) a = fmaf(pre_w[r * HD + j], xS[j * HD + c], a);
        wS[idx] = a;
    }
    if (tid < HD) {
        float a = 0.0f;
#pragma unroll 8
        for (int j = 0; j < HD; j++) a = fmaf(pre_b[j], xS[j * HD + tid], a);
        bS[tid] = a;
    }
    if (blockIdx.x == 0 && tid < 8)
        ((float4*)(hws + (size_t)NN * HD))[tid] = make_float4(0.f, 0.f, 0.f, 0.f);
    __syncthreads();
    int tn = tid & 15, tf = tid >> 4;
    int f0 = tf * 4;
    float4 bv = ((const float4*)bS)[tf];
    int ntiles = (NN + 63) >> 6;
    for (int t = blockIdx.x; t < ntiles; t += gridDim.x) {
        int nb = t << 6;
        float acc[4][4];
#pragma unroll
        for (int i = 0; i < 4; i++)
#pragma unroll
            for (int j = 0; j < 4; j++) acc[i][j] = 0.0f;
        for (int kh = 0; kh < 2; kh++) {
            __syncthreads();
            {
                int n_l = tid >> 4;
                int k4l = tid & 15;
                for (int r = 0; r < 4; r++) {
                    int n = n_l + r * 16;
                    int row = nb + n;
                    float4 v = make_float4(0.f, 0.f, 0.f, 0.f);
                    if (row < NN) v = ((const float4*)(x + (size_t)row * FIN))[kh * 16 + k4l];
                    int g = n >> 2, nl2 = n & 3;
                    const float* vp = (const float*)&v;
#pragma unroll
                    for (int j = 0; j < 4; j++) {
                        int k = k4l * 4 + j;
                        int gp = g ^ (k & 15);
                        xS[k * 64 + gp * 4 + nl2] = vp[j];
                    }
                }
            }
            __syncthreads();
#pragma unroll 4
            for (int kl = 0; kl < 64; kl++) {
                int gp = tn ^ (kl & 15);
                float4 xv = *(const float4*)&xS[kl * 64 + gp * 4];
                float4 wv = *(const float4*)&wS[(kh * 64 + kl) * 64 + f0];
                acc[0][0] = fmaf(xv.x, wv.x, acc[0][0]); acc[0][1] = fmaf(xv.x, wv.y, acc[0][1]);
                acc[0][2] = fmaf(xv.x, wv.z, acc[0][2]); acc[0][3] = fmaf(xv.x, wv.w, acc[0][3]);
                acc[1][0] = fmaf(xv.y, wv.x, acc[1][0]); acc[1][1] = fmaf(xv.y, wv.y, acc[1][1]);
                acc[1][2] = fmaf(xv.y, wv.z, acc[1][2]); acc[1][3] = fmaf(xv.y, wv.w, acc[1][3]);
                acc[2][0] = fmaf(xv.z, wv.x, acc[2][0]); acc[2][1] = fmaf(xv.z, wv.y, acc[2][1]);
                acc[2][2] = fmaf(xv.z, wv.z, acc[2][2]); acc[2][3] = fmaf(xv.z, wv.w, acc[2][3]);
                acc[3][0] = fmaf(xv.w, wv.x, acc[3][0]); acc[3][1] = fmaf(xv.w, wv.y, acc[3][1]);
                acc[3][2] = fmaf(xv.w, wv.z, acc[3][2]); acc[3][3] = fmaf(xv.w, wv.w, acc[3][3]);
            }
        }
        int n0 = nb + tn * 4;
#pragma unroll
        for (int i = 0; i < 4; i++) {
            int n = n0 + i;
            if (n < NN) {
                float dn = di[n];
                __half2 p0 = __floats2half2_rn((acc[i][0] + bv.x) * dn, (acc[i][1] + bv.y) * dn);
                __half2 p1 = __floats2half2_rn((acc[i][2] + bv.z) * dn, (acc[i][3] + bv.w) * dn);
                __half2* o = (__half2*)(hws + (size_t)n * HD + f0);
                o[0] = p0; o[1] = p1;
            }
        }
    }
}

// =====================================================================
// Tiled GEMM 2: hws = half((h1 @ c2_w) * di)   [N,64]@[64,64], h1 fp16
// =====================================================================
__global__ __launch_bounds__(256) void conv_gemm_tiled(const __half* __restrict__ hin,
                                                       const float* __restrict__ w,
                                                       const float* __restrict__ di,
                                                       __half* __restrict__ hws) {
    __shared__ float wS[HD * HD];   // 16 KB
    __shared__ float xS[64 * HD];   // 16 KB
    int tid = threadIdx.x;
    for (int i = tid; i < HD * HD; i += 256) wS[i] = w[i];
    int tn = tid & 15, tf = tid >> 4;
    int f0 = tf * 4;
    int ntiles = (NN + 63) >> 6;
    for (int t = blockIdx.x; t < ntiles; t += gridDim.x) {
        int nb = t << 6;
        __syncthreads();
        {
            int n_l = tid >> 3;   // 0..31
            int k8 = tid & 7;     // 0..7
            union U { float4 f4; __half2 h2[4]; } u;
            for (int r = 0; r < 2; r++) {
                int n = n_l + r * 32;
                int row = nb + n;
                u.f4 = make_float4(0.f, 0.f, 0.f, 0.f);
                if (row < NN) u.f4 = ((const float4*)(hin + (size_t)row * HD))[k8];
                int g = n >> 2, nl2 = n & 3;
#pragma unroll
                for (int j = 0; j < 4; j++) {
                    float2 p = __half22float2(u.h2[j]);
                    int k = k8 * 8 + 2 * j;
                    int gp = g ^ (k & 15);
                    xS[k * 64 + gp * 4 + nl2] = p.x;
                    int k2 = k + 1;
                    int gp2 = g ^ (k2 & 15);
                    xS[k2 * 64 + gp2 * 4 + nl2] = p.y;
                }
            }
        }
        __syncthreads();
        float acc[4][4];
#pragma unroll
        for (int i = 0; i < 4; i++)
#pragma unroll
            for (int j = 0; j < 4; j++) acc[i][j] = 0.0f;
#pragma unroll 4
        for (int k = 0; k < HD; k++) {
            int gp = tn ^ (k & 15);
            float4 xv = *(const float4*)&xS[k * 64 + gp * 4];
            float4 wv = *(const float4*)&wS[k * 64 + f0];
            acc[0][0] = fmaf(xv.x, wv.x, acc[0][0]); acc[0][1] = fmaf(xv.x, wv.y, acc[0][1]);
            acc[0][2] = fmaf(xv.x, wv.z, acc[0][2]); acc[0][3] = fmaf(xv.x, wv.w, acc[0][3]);
            acc[1][0] = fmaf(xv.y, wv.x, acc[1][0]); acc[1][1] = fmaf(xv.y, wv.y, acc[1][1]);
            acc[1][2] = fmaf(xv.y, wv.z, acc[1][2]); acc[1][3] = fmaf(xv.y, wv.w, acc[1][3]);
            acc[2][0] = fmaf(xv.z, wv.x, acc[2][0]); acc[2][1] = fmaf(xv.z, wv.y, acc[2][1]);
            acc[2][2] = fmaf(xv.z, wv.z, acc[2][2]); acc[2][3] = fmaf(xv.z, wv.w, acc[2][3]);
            acc[3][0] = fmaf(xv.w, wv.x, acc[3][0]); acc[3][1] = fmaf(xv.w, wv.y, acc[3][1]);
            acc[3][2] = fmaf(xv.w, wv.z, acc[3][2]); acc[3][3] = fmaf(xv.w, wv.w, acc[3][3]);
        }
        int n0 = nb + tn * 4;
#pragma unroll
        for (int i = 0; i < 4; i++) {
            int n = n0 + i;
            if (n < NN) {
                float dn = di[n];
                __half2 p0 = __floats2half2_rn(acc[i][0] * dn, acc[i][1] * dn);
                __half2 p1 = __floats2half2_rn(acc[i][2] * dn, acc[i][3] * dn);
                __half2* o = (__half2*)(hws + (size_t)n * HD + f0);
                o[0] = p0; o[1] = p1;
            }
        }
    }
}

// =====================================================================
// Gather core: lists padded to multiples of 8 (dummy src = NN -> zero
// row), so rounds are uniform, no guards. Unroll 2 rounds -> two
// independent dwordx4 loads in flight per wave (the R11 MLP fix).
// All __shfl executed by all 64 lanes.
// =====================================================================
__device__ __forceinline__ void gather_half(const int* __restrict__ offs,
                                            const int* __restrict__ pdeg,
                                            const unsigned int* __restrict__ ssrc,
                                            const __half* __restrict__ hws,
                                            int node, int lane, int fp, int rsub,
                                            float acc[8]) {
    int beg = offs[node];
    int end = beg + pdeg[node];
    union U { float4 f4; __half2 h2[4]; } u0, u1;
    __half2 hacc[4];
#pragma unroll
    for (int t = 0; t < 4; t++) hacc[t] = __floats2half2_rn(0.0f, 0.0f);
    if (rsub == 0) {  // self-loop term counted once
        u0.f4 = ((const float4*)(hws + (size_t)node * HD))[fp];
#pragma unroll
        for (int t = 0; t < 4; t++) hacc[t] = __hadd2(hacc[t], u0.h2[t]);
    }
    for (int i = beg; i < end; i += 64) {
        int cnt = end - i;
        if (cnt > 64) cnt = 64;                 // cnt is a multiple of 8
        int sl = (lane < cnt) ? (int)ssrc[i + lane] : 0;
        int j = 0;
        for (; j + 16 <= cnt; j += 16) {
            int s0 = __shfl(sl, j + rsub, 64);
            int s1 = __shfl(sl, j + 8 + rsub, 64);
            u0.f4 = ((const float4*)(hws + (size_t)s0 * HD))[fp];
            u1.f4 = ((const float4*)(hws + (size_t)s1 * HD))[fp];
#pragma unroll
            for (int t = 0; t < 4; t++) hacc[t] = __hadd2(hacc[t], u0.h2[t]);
#pragma unroll
            for (int t = 0; t < 4; t++) hacc[t] = __hadd2(hacc[t], u1.h2[t]);
        }
        if (j < cnt) {                          // exactly one full round
            int s0 = __shfl(sl, j + rsub, 64);
            u0.f4 = ((const float4*)(hws + (size_t)s0 * HD))[fp];
#pragma unroll
            for (int t = 0; t < 4; t++) hacc[t] = __hadd2(hacc[t], u0.h2[t]);
        }
    }
#pragma unroll
    for (int t = 0; t < 4; t++) {
        float2 p = __half22float2(hacc[t]);
        acc[2 * t] = p.x; acc[2 * t + 1] = p.y;
    }
#pragma unroll
    for (int t = 0; t < 8; t++) {
        acc[t] += __shfl_xor(acc[t], 8, 64);
        acc[t] += __shfl_xor(acc[t], 16, 64);
        acc[t] += __shfl_xor(acc[t], 32, 64);
    }
}

// LN over the 8-features-per-lane layout; returns relu'd y[8].
__device__ __forceinline__ void ln8(float v[8], int fp,
                                    const float* __restrict__ g,
                                    const float* __restrict__ bb,
                                    float y[8]) {
    float su = 0.0f;
#pragma unroll
    for (int t = 0; t < 8; t++) su += v[t];
    su += __shfl_xor(su, 1, 64); su += __shfl_xor(su, 2, 64); su += __shfl_xor(su, 4, 64);
    float mu = su * (1.0f / HD);
    float q = 0.0f;
#pragma unroll
    for (int t = 0; t < 8; t++) { float d = v[t] - mu; q += d * d; }
    q += __shfl_xor(q, 1, 64); q += __shfl_xor(q, 2, 64); q += __shfl_xor(q, 4, 64);
    float rstd = rsqrtf(q * (1.0f / HD) + 1e-5f);
    float4 ga = ((const float4*)g)[fp * 2], gb = ((const float4*)g)[fp * 2 + 1];
    float4 ba = ((const float4*)bb)[fp * 2], bc = ((const float4*)bb)[fp * 2 + 1];
    float gv[8] = {ga.x, ga.y, ga.z, ga.w, gb.x, gb.y, gb.z, gb.w};
    float bv[8] = {ba.x, ba.y, ba.z, ba.w, bc.x, bc.y, bc.z, bc.w};
#pragma unroll
    for (int t = 0; t < 8; t++) y[t] = fmaxf((v[t] - mu) * rstd * gv[t] + bv[t], 0.0f);
}

// ---------------- layer-1 gather + bias + LN + ReLU -> h1 (fp16) ----------------
__global__ __launch_bounds__(256) void gather_ln(const int* __restrict__ offs,
                                                 const int* __restrict__ pdeg,
                                                 const unsigned int* __restrict__ ssrc,
                                                 const float* __restrict__ di,
                                                 const __half* __restrict__ hws,
                                                 const float* __restrict__ cb,
                                                 const float* __restrict__ g,
                                                 const float* __restrict__ bb,
                                                 __half* __restrict__ out) {
    int wv = threadIdx.x >> 6;
    int lane = threadIdx.x & 63;
    int fp = lane & 7, rsub = lane >> 3;
    int node = blockIdx.x * 4 + wv;      // NN % 4 == 0
    float acc[8];
    gather_half(offs, pdeg, ssrc, hws, node, lane, fp, rsub, acc);
    float dn = di[node];
    float4 ca = ((const float4*)cb)[fp * 2], cc = ((const float4*)cb)[fp * 2 + 1];
    float cv[8] = {ca.x, ca.y, ca.z, ca.w, cc.x, cc.y, cc.z, cc.w};
    float v[8], y[8];
#pragma unroll
    for (int t = 0; t < 8; t++) v[t] = acc[t] * dn + cv[t];
    ln8(v, fp, g, bb, y);
    if (rsub == 0) {
        union U { float4 f4; __half2 h2[4]; } u;
#pragma unroll
        for (int t = 0; t < 4; t++) u.h2[t] = __floats2half2_rn(y[2 * t], y[2 * t + 1]);
        ((float4*)(out + (size_t)node * HD))[fp] = u.f4;
    }
}

// ---------------- layer-2 gather + LN + ReLU + skip + pooled scatter ----------------
__global__ __launch_bounds__(256) void gather_ln_pool(const int* __restrict__ offs,
                                                      const int* __restrict__ pdeg,
                                                      const unsigned int* __restrict__ ssrc,
                                                      const float* __restrict__ di,
                                                      const __half* __restrict__ hws,
                                                      const float* __restrict__ cb,
                                                      const float* __restrict__ g,
                                                      const float* __restrict__ bb,
                                                      const __half* __restrict__ h1,
                                                      const int* __restrict__ batch,
                                                      float* __restrict__ readout) {
    __shared__ float ls[4][HD];
    __shared__ int lb[4];
    int wv = threadIdx.x >> 6;
    int lane = threadIdx.x & 63;
    int fp = lane & 7, rsub = lane >> 3;
    int node = blockIdx.x * 4 + wv;
    float acc[8];
    gather_half(offs, pdeg, ssrc, hws, node, lane, fp, rsub, acc);
    float dn = di[node];
    float4 ca = ((const float4*)cb)[fp * 2], cc = ((const float4*)cb)[fp * 2 + 1];
    float cv[8] = {ca.x, ca.y, ca.z, ca.w, cc.x, cc.y, cc.z, cc.w};
    float v[8], y[8];
#pragma unroll
    for (int t = 0; t < 8; t++) v[t] = acc[t] * dn + cv[t];
    ln8(v, fp, g, bb, y);
    if (rsub == 0) {
        union U { float4 f4; __half2 h2[4]; } u;
        u.f4 = ((const float4*)(h1 + (size_t)node * HD))[fp];
        float* lrow = &ls[wv][fp * 8];
#pragma unroll
        for (int t = 0; t < 4; t++) {
            float2 p = __half22float2(u.h2[t]);
            lrow[2 * t] = y[2 * t] + p.x;
            lrow[2 * t + 1] = y[2 * t + 1] + p.y;
        }
    }
    if (lane == 0) lb[wv] = batch[node];
    __syncthreads();
    int f = lane;
    bool same = (lb[0] == lb[1]) && (lb[1] == lb[2]) && (lb[2] == lb[3]);
    if (same) {
        if (wv == 0) {
            float s4 = ls[0][f] + ls[1][f] + ls[2][f] + ls[3][f];
            atomicAdd(&readout[(size_t)lb[0] * HD + f], s4);
        }
    } else {
        atomicAdd(&readout[(size_t)lb[wv] * HD + f], ls[wv][f]);
    }
}

// ---------------- final: out = readout @ post_w + post_b  [G,64]@[64,40] ----------------
__global__ __launch_bounds__(256) void out_gemm(const float* __restrict__ r,
                                                const float* __restrict__ w,
                                                const float* __restrict__ b,
                                                float* __restrict__ out) {
    __shared__ float lw[HD * CO];
    for (int i = threadIdx.x; i < HD * CO; i += 256) lw[i] = w[i];
    __syncthreads();
    int grp = blockIdx.x * 4 + (threadIdx.x >> 6);
    int c = threadIdx.x & 63;
    if (grp >= NG || c >= CO) return;
    const float* rr = r + (size_t)grp * HD;
    float acc = b[c];
#pragma unroll 8
    for (int k = 0; k < HD; k++) acc = fmaf(rr[k], lw[k * CO + c], acc);
    out[(size_t)grp * CO + c] = acc;
}

extern "C" void kernel_launch(void* const* d_in, const int* in_sizes, int n_in,
                              void* d_out, int out_size, void* d_ws, size_t ws_size,
                              hipStream_t stream) {
    const float* x      = (const float*)d_in[0];
    const int*   ei     = (const int*)d_in[1];
    const int*   batch  = (const int*)d_in[2];
    const float* pre_w  = (const float*)d_in[3];
    const float* pre_b  = (const float*)d_in[4];
    const float* c1_w   = (const float*)d_in[5];
    const float* c1_b   = (const float*)d_in[6];
    const float* n1_g   = (const float*)d_in[7];
    const float* n1_b   = (const float*)d_in[8];
    const float* c2_w   = (const float*)d_in[9];
    const float* c2_b   = (const float*)d_in[10];
    const float* n2_g   = (const float*)d_in[11];
    const float* n2_b   = (const float*)d_in[12];
    const float* post_w = (const float*)d_in[13];
    const float* post_b = (const float*)d_in[14];

    const int* src = ei;
    const int* dst = ei + NE;

    char* p = (char*)d_ws;
    int*          ccur    = (int*)p;          p += (size_t)NBUK * 16 * 4;
    int*          offs    = (int*)p;          p += (size_t)NN * 4;
    int*          degn    = (int*)p;          p += (size_t)NN * 4;
    float*        di      = (float*)p;        p += (size_t)NN * 4;
    unsigned int* tmp     = (unsigned int*)p; p += (size_t)NBUK * BCAP * 4;
    unsigned int* ssrc    = (unsigned int*)p; p += (size_t)NBUK * PCAP * 4;
    float*        readout = (float*)p;        p += (size_t)NG * HD * 4;
    __half*       hws     = (__half*)p;       p += (size_t)(NN + 8) * HD * 2;  // +dummy row
    __half*       h1      = (__half*)p;       p += (size_t)NN * HD * 2;

    hipMemsetAsync(readout, 0, (size_t)NG * HD * 4, stream);

    // hierarchical CSR build (binned scatter -> padded per-bucket counting sort)
    init_kernel<<<(NBUK + 255) / 256, 256, 0, stream>>>(ccur);
    scatter_binned<<<NSCAT, 256, 0, stream>>>(src, dst, ccur, tmp);
    bucket_sort<<<NBUK, 256, 0, stream>>>(ccur, tmp, ssrc, offs, degn, di);

    // layer 1 (weff/beff fused into gemm1 prologue)
    gemm1_tiled<<<768, 256, 0, stream>>>(x, pre_w, pre_b, c1_w, di, hws);
    gather_ln<<<NN / 4, 256, 0, stream>>>(offs, degn, ssrc, di, hws, c1_b, n1_g, n1_b, h1);

    // layer 2
    conv_gemm_tiled<<<1280, 256, 0, stream>>>(h1, c2_w, di, hws);
    gather_ln_pool<<<NN / 4, 256, 0, stream>>>(offs, degn, ssrc, di, hws, c2_b, n2_g, n2_b, h1, batch, readout);

    out_gemm<<<(NG + 3) / 4, 256, 0, stream>>>(readout, post_w, post_b, (float*)d_out);
}

// Round 13
// 319.369 us; speedup vs baseline: 1.1551x; 1.1551x over previous
//
#include <hip/hip_runtime.h>
#include <hip/hip_fp16.h>

#define NN 100000
#define NE 1600000
#define FIN 128
#define HD 64
#define CO 40
#define NG 2048
#define NBUK 782          // ceil(NN/128)
#define BCAP 3072         // tmp bucket capacity
#define PCAP 3584         // padded ssrc capacity
#define CHUNK 4096        // edges per scatter block
#define NSCAT ((NE + CHUNK - 1) / CHUNK)   // 391

// ---------------- init padded cursors ----------------
__global__ __launch_bounds__(256) void init_kernel(int* __restrict__ ccur) {
    int b = blockIdx.x * 256 + threadIdx.x;
    if (b < NBUK) ccur[b * 16] = b * BCAP;
}

// =====================================================================
// Two-phase binned scatter: block-private ranges -> dense line assembly.
// =====================================================================
__global__ __launch_bounds__(256) void scatter_binned(const int* __restrict__ src,
                                                      const int* __restrict__ dst,
                                                      int* __restrict__ ccur,
                                                      unsigned int* __restrict__ tmp) {
    __shared__ int hist[NBUK];
    __shared__ int gbase[NBUK];
    int tid = threadIdx.x;
    int e0 = blockIdx.x * CHUNK;
    int e1 = e0 + CHUNK; if (e1 > NE) e1 = NE;
    for (int i = tid; i < NBUK; i += 256) hist[i] = 0;
    __syncthreads();
    for (int e = e0 + tid; e < e1; e += 256) atomicAdd(&hist[dst[e] >> 7], 1);
    __syncthreads();
    for (int b = tid; b < NBUK; b += 256) {
        int c = hist[b];
        gbase[b] = (c > 0) ? atomicAdd(&ccur[b * 16], c) : 0;
    }
    __syncthreads();
    for (int b = tid; b < NBUK; b += 256) hist[b] = 0;
    __syncthreads();
    for (int e = e0 + tid; e < e1; e += 256) {
        int d = dst[e];
        int s = src[e];
        int b = d >> 7;
        int p = atomicAdd(&hist[b], 1);
        tmp[gbase[b] + p] = ((unsigned int)(d & 127) << 17) | (unsigned int)s;
    }
}

// =====================================================================
// Per-bucket counting sort -> ssrc padded to multiples of 8 (dummy = NN).
// =====================================================================
__global__ __launch_bounds__(256) void bucket_sort(const int* __restrict__ ccur,
                                                   const unsigned int* __restrict__ tmp,
                                                   unsigned int* __restrict__ ssrc,
                                                   int* __restrict__ offs,
                                                   int* __restrict__ degn,
                                                   float* __restrict__ di) {
    __shared__ int lh[128];
    __shared__ int ls[128];
    __shared__ int lcur[128];
    __shared__ unsigned int lsorted[PCAP];
    int b = blockIdx.x;
    int tid = threadIdx.x;
    int base = b * BCAP;
    int cnt = ccur[b * 16] - base;
    if (tid < 128) lh[tid] = 0;
    __syncthreads();
    for (int i = tid; i < cnt; i += 256) {
        unsigned int u = tmp[base + i];
        atomicAdd(&lh[(u >> 17) & 127], 1);
    }
    __syncthreads();
    int pd = 0;
    if (tid < 128) { pd = (lh[tid] + 7) & ~7; ls[tid] = pd; }
    __syncthreads();
    for (int off = 1; off < 128; off <<= 1) {
        int v = 0;
        if (tid < 128 && tid >= off) v = ls[tid - off];
        __syncthreads();
        if (tid < 128) ls[tid] += v;
        __syncthreads();
    }
    if (tid < 128) {
        int pexcl = ls[tid] - pd;
        lcur[tid] = pexcl;
        int node = b * 128 + tid;
        if (node < NN) {
            offs[node] = b * PCAP + pexcl;
            degn[node] = pd;
            di[node] = rsqrtf((float)lh[tid] + 1.0f);
        }
    }
    __syncthreads();
    int total = ls[127];
    for (int i = tid; i < total; i += 256) lsorted[i] = (unsigned int)NN;
    __syncthreads();
    for (int i = tid; i < cnt; i += 256) {
        unsigned int u = tmp[base + i];
        int dl = (u >> 17) & 127;
        int pos = atomicAdd(&lcur[dl], 1);
        lsorted[pos] = u & 0x1FFFFu;
    }
    __syncthreads();
    for (int i = tid; i < total; i += 256) ssrc[(size_t)b * PCAP + i] = lsorted[i];
}

// ---------------- W_eff = pre_w @ c1_w ; b_eff = pre_b @ c1_w (one-shot) ----------------
__global__ __launch_bounds__(256) void weff_kernel(const float* __restrict__ pre_w,
                                                   const float* __restrict__ pre_b,
                                                   const float* __restrict__ c1_w,
                                                   float* __restrict__ weff,
                                                   float* __restrict__ beff) {
    if (blockIdx.x < 32) {
        int o = blockIdx.x * 256 + threadIdx.x;  // [0, 8192)
        int r = o >> 6, c = o & 63;
        float acc = 0.0f;
#pragma unroll 8
        for (int k = 0; k < HD; k++) acc = fmaf(pre_w[r * HD + k], c1_w[k * HD + c], acc);
        weff[o] = acc;
    } else {
        int c = threadIdx.x;
        if (c < HD) {
            float acc = 0.0f;
#pragma unroll 8
            for (int k = 0; k < HD; k++) acc = fmaf(pre_b[k], c1_w[k * HD + c], acc);
            beff[c] = acc;
        }
    }
}

// =====================================================================
// Tiled GEMM 1: hws = half((x @ W_eff + b_eff) * di)   [N,128]@[128,64]
// =====================================================================
__global__ __launch_bounds__(256) void gemm1_tiled(const float* __restrict__ x,
                                                   const float* __restrict__ w,
                                                   const float* __restrict__ b,
                                                   const float* __restrict__ di,
                                                   __half* __restrict__ hws) {
    __shared__ float wS[FIN * HD];   // 32 KB
    __shared__ float xS[64 * 64];    // 16 KB (one K-half)
    int tid = threadIdx.x;
    for (int i = tid; i < FIN * HD; i += 256) wS[i] = w[i];
    int tn = tid & 15, tf = tid >> 4;
    int f0 = tf * 4;
    float4 bv = ((const float4*)b)[tf];
    int ntiles = (NN + 63) >> 6;
    for (int t = blockIdx.x; t < ntiles; t += gridDim.x) {
        int nb = t << 6;
        float acc[4][4];
#pragma unroll
        for (int i = 0; i < 4; i++)
#pragma unroll
            for (int j = 0; j < 4; j++) acc[i][j] = 0.0f;
        for (int kh = 0; kh < 2; kh++) {
            __syncthreads();
            {
                int n_l = tid >> 4;
                int k4l = tid & 15;
                for (int r = 0; r < 4; r++) {
                    int n = n_l + r * 16;
                    int row = nb + n;
                    float4 v = make_float4(0.f, 0.f, 0.f, 0.f);
                    if (row < NN) v = ((const float4*)(x + (size_t)row * FIN))[kh * 16 + k4l];
                    int g = n >> 2, nl2 = n & 3;
                    const float* vp = (const float*)&v;
#pragma unroll
                    for (int j = 0; j < 4; j++) {
                        int k = k4l * 4 + j;
                        int gp = g ^ (k & 15);
                        xS[k * 64 + gp * 4 + nl2] = vp[j];
                    }
                }
            }
            __syncthreads();
#pragma unroll 4
            for (int kl = 0; kl < 64; kl++) {
                int gp = tn ^ (kl & 15);
                float4 xv = *(const float4*)&xS[kl * 64 + gp * 4];
                float4 wv = *(const float4*)&wS[(kh * 64 + kl) * 64 + f0];
                acc[0][0] = fmaf(xv.x, wv.x, acc[0][0]); acc[0][1] = fmaf(xv.x, wv.y, acc[0][1]);
                acc[0][2] = fmaf(xv.x, wv.z, acc[0][2]); acc[0][3] = fmaf(xv.x, wv.w, acc[0][3]);
                acc[1][0] = fmaf(xv.y, wv.x, acc[1][0]); acc[1][1] = fmaf(xv.y, wv.y, acc[1][1]);
                acc[1][2] = fmaf(xv.y, wv.z, acc[1][2]); acc[1][3] = fmaf(xv.y, wv.w, acc[1][3]);
                acc[2][0] = fmaf(xv.z, wv.x, acc[2][0]); acc[2][1] = fmaf(xv.z, wv.y, acc[2][1]);
                acc[2][2] = fmaf(xv.z, wv.z, acc[2][2]); acc[2][3] = fmaf(xv.z, wv.w, acc[2][3]);
                acc[3][0] = fmaf(xv.w, wv.x, acc[3][0]); acc[3][1] = fmaf(xv.w, wv.y, acc[3][1]);
                acc[3][2] = fmaf(xv.w, wv.z, acc[3][2]); acc[3][3] = fmaf(xv.w, wv.w, acc[3][3]);
            }
        }
        int n0 = nb + tn * 4;
#pragma unroll
        for (int i = 0; i < 4; i++) {
            int n = n0 + i;
            if (n < NN) {
                float dn = di[n];
                __half2 p0 = __floats2half2_rn((acc[i][0] + bv.x) * dn, (acc[i][1] + bv.y) * dn);
                __half2 p1 = __floats2half2_rn((acc[i][2] + bv.z) * dn, (acc[i][3] + bv.w) * dn);
                __half2* o = (__half2*)(hws + (size_t)n * HD + f0);
                o[0] = p0; o[1] = p1;
            }
        }
    }
}

// =====================================================================
// Tiled GEMM 2: hws = half((h1 @ c2_w) * di)   [N,64]@[64,64], h1 fp16
// =====================================================================
__global__ __launch_bounds__(256) void conv_gemm_tiled(const __half* __restrict__ hin,
                                                       const float* __restrict__ w,
                                                       const float* __restrict__ di,
                                                       __half* __restrict__ hws) {
    __shared__ float wS[HD * HD];   // 16 KB
    __shared__ float xS[64 * HD];   // 16 KB
    int tid = threadIdx.x;
    for (int i = tid; i < HD * HD; i += 256) wS[i] = w[i];
    int tn = tid & 15, tf = tid >> 4;
    int f0 = tf * 4;
    int ntiles = (NN + 63) >> 6;
    for (int t = blockIdx.x; t < ntiles; t += gridDim.x) {
        int nb = t << 6;
        __syncthreads();
        {
            int n_l = tid >> 3;   // 0..31
            int k8 = tid & 7;     // 0..7
            union U { float4 f4; __half2 h2[4]; } u;
            for (int r = 0; r < 2; r++) {
                int n = n_l + r * 32;
                int row = nb + n;
                u.f4 = make_float4(0.f, 0.f, 0.f, 0.f);
                if (row < NN) u.f4 = ((const float4*)(hin + (size_t)row * HD))[k8];
                int g = n >> 2, nl2 = n & 3;
#pragma unroll
                for (int j = 0; j < 4; j++) {
                    float2 p = __half22float2(u.h2[j]);
                    int k = k8 * 8 + 2 * j;
                    int gp = g ^ (k & 15);
                    xS[k * 64 + gp * 4 + nl2] = p.x;
                    int k2 = k + 1;
                    int gp2 = g ^ (k2 & 15);
                    xS[k2 * 64 + gp2 * 4 + nl2] = p.y;
                }
            }
        }
        __syncthreads();
        float acc[4][4];
#pragma unroll
        for (int i = 0; i < 4; i++)
#pragma unroll
            for (int j = 0; j < 4; j++) acc[i][j] = 0.0f;
#pragma unroll 4
        for (int k = 0; k < HD; k++) {
            int gp = tn ^ (k & 15);
            float4 xv = *(const float4*)&xS[k * 64 + gp * 4];
            float4 wv = *(const float4*)&wS[k * 64 + f0];
            acc[0][0] = fmaf(xv.x, wv.x, acc[0][0]); acc[0][1] = fmaf(xv.x, wv.y, acc[0][1]);
            acc[0][2] = fmaf(xv.x, wv.z, acc[0][2]); acc[0][3] = fmaf(xv.x, wv.w, acc[0][3]);
            acc[1][0] = fmaf(xv.y, wv.x, acc[1][0]); acc[1][1] = fmaf(xv.y, wv.y, acc[1][1]);
            acc[1][2] = fmaf(xv.y, wv.z, acc[1][2]); acc[1][3] = fmaf(xv.y, wv.w, acc[1][3]);
            acc[2][0] = fmaf(xv.z, wv.x, acc[2][0]); acc[2][1] = fmaf(xv.z, wv.y, acc[2][1]);
            acc[2][2] = fmaf(xv.z, wv.z, acc[2][2]); acc[2][3] = fmaf(xv.z, wv.w, acc[2][3]);
            acc[3][0] = fmaf(xv.w, wv.x, acc[3][0]); acc[3][1] = fmaf(xv.w, wv.y, acc[3][1]);
            acc[3][2] = fmaf(xv.w, wv.z, acc[3][2]); acc[3][3] = fmaf(xv.w, wv.w, acc[3][3]);
        }
        int n0 = nb + tn * 4;
#pragma unroll
        for (int i = 0; i < 4; i++) {
            int n = n0 + i;
            if (n < NN) {
                float dn = di[n];
                __half2 p0 = __floats2half2_rn(acc[i][0] * dn, acc[i][1] * dn);
                __half2 p1 = __floats2half2_rn(acc[i][2] * dn, acc[i][3] * dn);
                __half2* o = (__half2*)(hws + (size_t)n * HD + f0);
                o[0] = p0; o[1] = p1;
            }
        }
    }
}

// =====================================================================
// Gather core: padded lists (multiple of 8, dummy src = NN -> zero row),
// uniform rounds, unroll 2 -> two dwordx4 loads in flight per wave.
// =====================================================================
__device__ __forceinline__ void gather_half(const int* __restrict__ offs,
                                            const int* __restrict__ pdeg,
                                            const unsigned int* __restrict__ ssrc,
                                            const __half* __restrict__ hws,
                                            int node, int lane, int fp, int rsub,
                                            float acc[8]) {
    int beg = offs[node];
    int end = beg + pdeg[node];
    union U { float4 f4; __half2 h2[4]; } u0, u1;
    __half2 hacc[4];
#pragma unroll
    for (int t = 0; t < 4; t++) hacc[t] = __floats2half2_rn(0.0f, 0.0f);
    if (rsub == 0) {
        u0.f4 = ((const float4*)(hws + (size_t)node * HD))[fp];
#pragma unroll
        for (int t = 0; t < 4; t++) hacc[t] = __hadd2(hacc[t], u0.h2[t]);
    }
    for (int i = beg; i < end; i += 64) {
        int cnt = end - i;
        if (cnt > 64) cnt = 64;                 // multiple of 8
        int sl = (lane < cnt) ? (int)ssrc[i + lane] : 0;
        int j = 0;
        for (; j + 16 <= cnt; j += 16) {
            int s0 = __shfl(sl, j + rsub, 64);
            int s1 = __shfl(sl, j + 8 + rsub, 64);
            u0.f4 = ((const float4*)(hws + (size_t)s0 * HD))[fp];
            u1.f4 = ((const float4*)(hws + (size_t)s1 * HD))[fp];
#pragma unroll
            for (int t = 0; t < 4; t++) hacc[t] = __hadd2(hacc[t], u0.h2[t]);
#pragma unroll
            for (int t = 0; t < 4; t++) hacc[t] = __hadd2(hacc[t], u1.h2[t]);
        }
        if (j < cnt) {
            int s0 = __shfl(sl, j + rsub, 64);
            u0.f4 = ((const float4*)(hws + (size_t)s0 * HD))[fp];
#pragma unroll
            for (int t = 0; t < 4; t++) hacc[t] = __hadd2(hacc[t], u0.h2[t]);
        }
    }
#pragma unroll
    for (int t = 0; t < 4; t++) {
        float2 p = __half22float2(hacc[t]);
        acc[2 * t] = p.x; acc[2 * t + 1] = p.y;
    }
#pragma unroll
    for (int t = 0; t < 8; t++) {
        acc[t] += __shfl_xor(acc[t], 8, 64);
        acc[t] += __shfl_xor(acc[t], 16, 64);
        acc[t] += __shfl_xor(acc[t], 32, 64);
    }
}

// LN over the 8-features-per-lane layout; returns relu'd y[8].
__device__ __forceinline__ void ln8(float v[8], int fp,
                                    const float* __restrict__ g,
                                    const float* __restrict__ bb,
                                    float y[8]) {
    float su = 0.0f;
#pragma unroll
    for (int t = 0; t < 8; t++) su += v[t];
    su += __shfl_xor(su, 1, 64); su += __shfl_xor(su, 2, 64); su += __shfl_xor(su, 4, 64);
    float mu = su * (1.0f / HD);
    float q = 0.0f;
#pragma unroll
    for (int t = 0; t < 8; t++) { float d = v[t] - mu; q += d * d; }
    q += __shfl_xor(q, 1, 64); q += __shfl_xor(q, 2, 64); q += __shfl_xor(q, 4, 64);
    float rstd = rsqrtf(q * (1.0f / HD) + 1e-5f);
    float4 ga = ((const float4*)g)[fp * 2], gb = ((const float4*)g)[fp * 2 + 1];
    float4 ba = ((const float4*)bb)[fp * 2], bc = ((const float4*)bb)[fp * 2 + 1];
    float gv[8] = {ga.x, ga.y, ga.z, ga.w, gb.x, gb.y, gb.z, gb.w};
    float bv[8] = {ba.x, ba.y, ba.z, ba.w, bc.x, bc.y, bc.z, bc.w};
#pragma unroll
    for (int t = 0; t < 8; t++) y[t] = fmaxf((v[t] - mu) * rstd * gv[t] + bv[t], 0.0f);
}

// ---------------- layer-1 gather + bias + LN + ReLU -> h1 (fp16) ----------------
__global__ __launch_bounds__(256) void gather_ln(const int* __restrict__ offs,
                                                 const int* __restrict__ pdeg,
                                                 const unsigned int* __restrict__ ssrc,
                                                 const float* __restrict__ di,
                                                 const __half* __restrict__ hws,
                                                 const float* __restrict__ cb,
                                                 const float* __restrict__ g,
                                                 const float* __restrict__ bb,
                                                 __half* __restrict__ out) {
    int wv = threadIdx.x >> 6;
    int lane = threadIdx.x & 63;
    int fp = lane & 7, rsub = lane >> 3;
    int node = blockIdx.x * 4 + wv;      // NN % 4 == 0
    float acc[8];
    gather_half(offs, pdeg, ssrc, hws, node, lane, fp, rsub, acc);
    float dn = di[node];
    float4 ca = ((const float4*)cb)[fp * 2], cc = ((const float4*)cb)[fp * 2 + 1];
    float cv[8] = {ca.x, ca.y, ca.z, ca.w, cc.x, cc.y, cc.z, cc.w};
    float v[8], y[8];
#pragma unroll
    for (int t = 0; t < 8; t++) v[t] = acc[t] * dn + cv[t];
    ln8(v, fp, g, bb, y);
    if (rsub == 0) {
        union U { float4 f4; __half2 h2[4]; } u;
#pragma unroll
        for (int t = 0; t < 4; t++) u.h2[t] = __floats2half2_rn(y[2 * t], y[2 * t + 1]);
        ((float4*)(out + (size_t)node * HD))[fp] = u.f4;
    }
}

// ---------------- layer-2 gather + LN + ReLU + skip + pooled scatter ----------------
__global__ __launch_bounds__(256) void gather_ln_pool(const int* __restrict__ offs,
                                                      const int* __restrict__ pdeg,
                                                      const unsigned int* __restrict__ ssrc,
                                                      const float* __restrict__ di,
                                                      const __half* __restrict__ hws,
                                                      const float* __restrict__ cb,
                                                      const float* __restrict__ g,
                                                      const float* __restrict__ bb,
                                                      const __half* __restrict__ h1,
                                                      const int* __restrict__ batch,
                                                      float* __restrict__ readout) {
    __shared__ float ls[4][HD];
    __shared__ int lb[4];
    int wv = threadIdx.x >> 6;
    int lane = threadIdx.x & 63;
    int fp = lane & 7, rsub = lane >> 3;
    int node = blockIdx.x * 4 + wv;
    float acc[8];
    gather_half(offs, pdeg, ssrc, hws, node, lane, fp, rsub, acc);
    float dn = di[node];
    float4 ca = ((const float4*)cb)[fp * 2], cc = ((const float4*)cb)[fp * 2 + 1];
    float cv[8] = {ca.x, ca.y, ca.z, ca.w, cc.x, cc.y, cc.z, cc.w};
    float v[8], y[8];
#pragma unroll
    for (int t = 0; t < 8; t++) v[t] = acc[t] * dn + cv[t];
    ln8(v, fp, g, bb, y);
    if (rsub == 0) {
        union U { float4 f4; __half2 h2[4]; } u;
        u.f4 = ((const float4*)(h1 + (size_t)node * HD))[fp];
        float* lrow = &ls[wv][fp * 8];
#pragma unroll
        for (int t = 0; t < 4; t++) {
            float2 p = __half22float2(u.h2[t]);
            lrow[2 * t] = y[2 * t] + p.x;
            lrow[2 * t + 1] = y[2 * t + 1] + p.y;
        }
    }
    if (lane == 0) lb[wv] = batch[node];
    __syncthreads();
    int f = lane;
    bool same = (lb[0] == lb[1]) && (lb[1] == lb[2]) && (lb[2] == lb[3]);
    if (same) {
        if (wv == 0) {
            float s4 = ls[0][f] + ls[1][f] + ls[2][f] + ls[3][f];
            atomicAdd(&readout[(size_t)lb[0] * HD + f], s4);
        }
    } else {
        atomicAdd(&readout[(size_t)lb[wv] * HD + f], ls[wv][f]);
    }
}

// ---------------- final: out = readout @ post_w + post_b  [G,64]@[64,40] ----------------
__global__ __launch_bounds__(256) void out_gemm(const float* __restrict__ r,
                                                const float* __restrict__ w,
                                                const float* __restrict__ b,
                                                float* __restrict__ out) {
    __shared__ float lw[HD * CO];
    for (int i = threadIdx.x; i < HD * CO; i += 256) lw[i] = w[i];
    __syncthreads();
    int grp = blockIdx.x * 4 + (threadIdx.x >> 6);
    int c = threadIdx.x & 63;
    if (grp >= NG || c >= CO) return;
    const float* rr = r + (size_t)grp * HD;
    float acc = b[c];
#pragma unroll 8
    for (int k = 0; k < HD; k++) acc = fmaf(rr[k], lw[k * CO + c], acc);
    out[(size_t)grp * CO + c] = acc;
}

extern "C" void kernel_launch(void* const* d_in, const int* in_sizes, int n_in,
                              void* d_out, int out_size, void* d_ws, size_t ws_size,
                              hipStream_t stream) {
    const float* x      = (const float*)d_in[0];
    const int*   ei     = (const int*)d_in[1];
    const int*   batch  = (const int*)d_in[2];
    const float* pre_w  = (const float*)d_in[3];
    const float* pre_b  = (const float*)d_in[4];
    const float* c1_w   = (const float*)d_in[5];
    const float* c1_b   = (const float*)d_in[6];
    const float* n1_g   = (const float*)d_in[7];
    const float* n1_b   = (const float*)d_in[8];
    const float* c2_w   = (const float*)d_in[9];
    const float* c2_b   = (const float*)d_in[10];
    const float* n2_g   = (const float*)d_in[11];
    const float* n2_b   = (const float*)d_in[12];
    const float* post_w = (const float*)d_in[13];
    const float* post_b = (const float*)d_in[14];

    const int* src = ei;
    const int* dst = ei + NE;

    char* p = (char*)d_ws;
    int*          ccur    = (int*)p;          p += (size_t)NBUK * 16 * 4;
    int*          offs    = (int*)p;          p += (size_t)NN * 4;
    int*          degn    = (int*)p;          p += (size_t)NN * 4;
    float*        di      = (float*)p;        p += (size_t)NN * 4;
    float*        weff    = (float*)p;        p += (size_t)FIN * HD * 4;
    float*        beff    = (float*)p;        p += 256;
    unsigned int* tmp     = (unsigned int*)p; p += (size_t)NBUK * BCAP * 4;
    unsigned int* ssrc    = (unsigned int*)p; p += (size_t)NBUK * PCAP * 4;
    float*        readout = (float*)p;        p += (size_t)NG * HD * 4;
    __half*       hws     = (__half*)p;       p += (size_t)(NN + 8) * HD * 2;  // +dummy row
    __half*       h1      = (__half*)p;       p += (size_t)NN * HD * 2;

    hipMemsetAsync(readout, 0, (size_t)NG * HD * 4, stream);
    hipMemsetAsync(hws + (size_t)NN * HD, 0, HD * 2, stream);  // dummy row NN = 0

    // hierarchical CSR build
    init_kernel<<<(NBUK + 255) / 256, 256, 0, stream>>>(ccur);
    scatter_binned<<<NSCAT, 256, 0, stream>>>(src, dst, ccur, tmp);
    bucket_sort<<<NBUK, 256, 0, stream>>>(ccur, tmp, ssrc, offs, degn, di);

    // Folded pre-MLP weights (one-shot kernel — NOT fused into gemm1; R12 showed 768x redundant prologue)
    weff_kernel<<<33, 256, 0, stream>>>(pre_w, pre_b, c1_w, weff, beff);

    // layer 1
    gemm1_tiled<<<768, 256, 0, stream>>>(x, weff, beff, di, hws);
    gather_ln<<<NN / 4, 256, 0, stream>>>(offs, degn, ssrc, di, hws, c1_b, n1_g, n1_b, h1);

    // layer 2
    conv_gemm_tiled<<<1280, 256, 0, stream>>>(h1, c2_w, di, hws);
    gather_ln_pool<<<NN / 4, 256, 0, stream>>>(offs, degn, ssrc, di, hws, c2_b, n2_g, n2_b, h1, batch, readout);

    out_gemm<<<(NG + 3) / 4, 256, 0, stream>>>(readout, post_w, post_b, (float*)d_out);
}

// Round 14
// 302.316 us; speedup vs baseline: 1.2203x; 1.0564x over previous
//
#include <hip/hip_runtime.h>
#include <hip/hip_fp16.h>

#define NN 100000
#define NE 1600000
#define FIN 128
#define HD 64
#define CO 40
#define NG 2048
#define NBUK 782          // ceil(NN/128)
#define BCAP 3072         // tmp bucket capacity
#define PCAP 3584         // padded ssrc capacity
#define CHUNK 4096        // edges per scatter block
#define NSCAT ((NE + CHUNK - 1) / CHUNK)   // 391

// ---------------- setup: cursors + zero readout + zero dummy hws row ----------------
__global__ __launch_bounds__(256) void setup_kernel(int* __restrict__ ccur,
                                                    float* __restrict__ readout,
                                                    unsigned int* __restrict__ dummy) {
    int gid = blockIdx.x * 256 + threadIdx.x;
    if (gid < NG * HD) readout[gid] = 0.0f;
    if (gid < NBUK) ccur[gid * 16] = gid * BCAP;
    if (gid < HD / 2) dummy[gid] = 0u;   // 64 halves = 32 uints
}

// =====================================================================
// Two-phase binned scatter: block-private ranges -> dense line assembly.
// =====================================================================
__global__ __launch_bounds__(256) void scatter_binned(const int* __restrict__ src,
                                                      const int* __restrict__ dst,
                                                      int* __restrict__ ccur,
                                                      unsigned int* __restrict__ tmp) {
    __shared__ int hist[NBUK];
    __shared__ int gbase[NBUK];
    int tid = threadIdx.x;
    int e0 = blockIdx.x * CHUNK;
    int e1 = e0 + CHUNK; if (e1 > NE) e1 = NE;
    for (int i = tid; i < NBUK; i += 256) hist[i] = 0;
    __syncthreads();
    for (int e = e0 + tid; e < e1; e += 256) atomicAdd(&hist[dst[e] >> 7], 1);
    __syncthreads();
    for (int b = tid; b < NBUK; b += 256) {
        int c = hist[b];
        gbase[b] = (c > 0) ? atomicAdd(&ccur[b * 16], c) : 0;
    }
    __syncthreads();
    for (int b = tid; b < NBUK; b += 256) hist[b] = 0;
    __syncthreads();
    for (int e = e0 + tid; e < e1; e += 256) {
        int d = dst[e];
        int s = src[e];
        int b = d >> 7;
        int p = atomicAdd(&hist[b], 1);
        tmp[gbase[b] + p] = ((unsigned int)(d & 127) << 17) | (unsigned int)s;
    }
}

// =====================================================================
// Per-bucket counting sort -> ssrc padded to multiples of 8 (dummy = NN).
// =====================================================================
__global__ __launch_bounds__(256) void bucket_sort(const int* __restrict__ ccur,
                                                   const unsigned int* __restrict__ tmp,
                                                   unsigned int* __restrict__ ssrc,
                                                   int* __restrict__ offs,
                                                   int* __restrict__ degn,
                                                   float* __restrict__ di) {
    __shared__ int lh[128];
    __shared__ int ls[128];
    __shared__ int lcur[128];
    __shared__ unsigned int lsorted[PCAP];
    int b = blockIdx.x;
    int tid = threadIdx.x;
    int base = b * BCAP;
    int cnt = ccur[b * 16] - base;
    if (tid < 128) lh[tid] = 0;
    __syncthreads();
    for (int i = tid; i < cnt; i += 256) {
        unsigned int u = tmp[base + i];
        atomicAdd(&lh[(u >> 17) & 127], 1);
    }
    __syncthreads();
    int pd = 0;
    if (tid < 128) { pd = (lh[tid] + 7) & ~7; ls[tid] = pd; }
    __syncthreads();
    for (int off = 1; off < 128; off <<= 1) {
        int v = 0;
        if (tid < 128 && tid >= off) v = ls[tid - off];
        __syncthreads();
        if (tid < 128) ls[tid] += v;
        __syncthreads();
    }
    if (tid < 128) {
        int pexcl = ls[tid] - pd;
        lcur[tid] = pexcl;
        int node = b * 128 + tid;
        if (node < NN) {
            offs[node] = b * PCAP + pexcl;
            degn[node] = pd;
            di[node] = rsqrtf((float)lh[tid] + 1.0f);
        }
    }
    __syncthreads();
    int total = ls[127];
    for (int i = tid; i < total; i += 256) lsorted[i] = (unsigned int)NN;
    __syncthreads();
    for (int i = tid; i < cnt; i += 256) {
        unsigned int u = tmp[base + i];
        int dl = (u >> 17) & 127;
        int pos = atomicAdd(&lcur[dl], 1);
        lsorted[pos] = u & 0x1FFFFu;
    }
    __syncthreads();
    for (int i = tid; i < total; i += 256) ssrc[(size_t)b * PCAP + i] = lsorted[i];
}

// ---------------- W_eff = pre_w @ c1_w ; b_eff = pre_b @ c1_w (one-shot) ----------------
__global__ __launch_bounds__(256) void weff_kernel(const float* __restrict__ pre_w,
                                                   const float* __restrict__ pre_b,
                                                   const float* __restrict__ c1_w,
                                                   float* __restrict__ weff,
                                                   float* __restrict__ beff) {
    if (blockIdx.x < 32) {
        int o = blockIdx.x * 256 + threadIdx.x;
        int r = o >> 6, c = o & 63;
        float acc = 0.0f;
#pragma unroll 8
        for (int k = 0; k < HD; k++) acc = fmaf(pre_w[r * HD + k], c1_w[k * HD + c], acc);
        weff[o] = acc;
    } else {
        int c = threadIdx.x;
        if (c < HD) {
            float acc = 0.0f;
#pragma unroll 8
            for (int k = 0; k < HD; k++) acc = fmaf(pre_b[k], c1_w[k * HD + c], acc);
            beff[c] = acc;
        }
    }
}

// =====================================================================
// Tiled GEMM 1: hws = half((x @ W_eff + b_eff) * di)   [N,128]@[128,64]
// =====================================================================
__global__ __launch_bounds__(256) void gemm1_tiled(const float* __restrict__ x,
                                                   const float* __restrict__ w,
                                                   const float* __restrict__ b,
                                                   const float* __restrict__ di,
                                                   __half* __restrict__ hws) {
    __shared__ float wS[FIN * HD];   // 32 KB
    __shared__ float xS[64 * 64];    // 16 KB (one K-half)
    int tid = threadIdx.x;
    for (int i = tid; i < FIN * HD; i += 256) wS[i] = w[i];
    int tn = tid & 15, tf = tid >> 4;
    int f0 = tf * 4;
    float4 bv = ((const float4*)b)[tf];
    int ntiles = (NN + 63) >> 6;
    for (int t = blockIdx.x; t < ntiles; t += gridDim.x) {
        int nb = t << 6;
        float acc[4][4];
#pragma unroll
        for (int i = 0; i < 4; i++)
#pragma unroll
            for (int j = 0; j < 4; j++) acc[i][j] = 0.0f;
        for (int kh = 0; kh < 2; kh++) {
            __syncthreads();
            {
                int n_l = tid >> 4;
                int k4l = tid & 15;
                for (int r = 0; r < 4; r++) {
                    int n = n_l + r * 16;
                    int row = nb + n;
                    float4 v = make_float4(0.f, 0.f, 0.f, 0.f);
                    if (row < NN) v = ((const float4*)(x + (size_t)row * FIN))[kh * 16 + k4l];
                    int g = n >> 2, nl2 = n & 3;
                    const float* vp = (const float*)&v;
#pragma unroll
                    for (int j = 0; j < 4; j++) {
                        int k = k4l * 4 + j;
                        int gp = g ^ (k & 15);
                        xS[k * 64 + gp * 4 + nl2] = vp[j];
                    }
                }
            }
            __syncthreads();
#pragma unroll 4
            for (int kl = 0; kl < 64; kl++) {
                int gp = tn ^ (kl & 15);
                float4 xv = *(const float4*)&xS[kl * 64 + gp * 4];
                float4 wv = *(const float4*)&wS[(kh * 64 + kl) * 64 + f0];
                acc[0][0] = fmaf(xv.x, wv.x, acc[0][0]); acc[0][1] = fmaf(xv.x, wv.y, acc[0][1]);
                acc[0][2] = fmaf(xv.x, wv.z, acc[0][2]); acc[0][3] = fmaf(xv.x, wv.w, acc[0][3]);
                acc[1][0] = fmaf(xv.y, wv.x, acc[1][0]); acc[1][1] = fmaf(xv.y, wv.y, acc[1][1]);
                acc[1][2] = fmaf(xv.y, wv.z, acc[1][2]); acc[1][3] = fmaf(xv.y, wv.w, acc[1][3]);
                acc[2][0] = fmaf(xv.z, wv.x, acc[2][0]); acc[2][1] = fmaf(xv.z, wv.y, acc[2][1]);
                acc[2][2] = fmaf(xv.z, wv.z, acc[2][2]); acc[2][3] = fmaf(xv.z, wv.w, acc[2][3]);
                acc[3][0] = fmaf(xv.w, wv.x, acc[3][0]); acc[3][1] = fmaf(xv.w, wv.y, acc[3][1]);
                acc[3][2] = fmaf(xv.w, wv.z, acc[3][2]); acc[3][3] = fmaf(xv.w, wv.w, acc[3][3]);
            }
        }
        int n0 = nb + tn * 4;
#pragma unroll
        for (int i = 0; i < 4; i++) {
            int n = n0 + i;
            if (n < NN) {
                float dn = di[n];
                __half2 p0 = __floats2half2_rn((acc[i][0] + bv.x) * dn, (acc[i][1] + bv.y) * dn);
                __half2 p1 = __floats2half2_rn((acc[i][2] + bv.z) * dn, (acc[i][3] + bv.w) * dn);
                __half2* o = (__half2*)(hws + (size_t)n * HD + f0);
                o[0] = p0; o[1] = p1;
            }
        }
    }
}

// =====================================================================
// Tiled GEMM 2: hws = half((h1 @ c2_w) * di)   [N,64]@[64,64], h1 fp16
// =====================================================================
__global__ __launch_bounds__(256) void conv_gemm_tiled(const __half* __restrict__ hin,
                                                       const float* __restrict__ w,
                                                       const float* __restrict__ di,
                                                       __half* __restrict__ hws) {
    __shared__ float wS[HD * HD];
    __shared__ float xS[64 * HD];
    int tid = threadIdx.x;
    for (int i = tid; i < HD * HD; i += 256) wS[i] = w[i];
    int tn = tid & 15, tf = tid >> 4;
    int f0 = tf * 4;
    int ntiles = (NN + 63) >> 6;
    for (int t = blockIdx.x; t < ntiles; t += gridDim.x) {
        int nb = t << 6;
        __syncthreads();
        {
            int n_l = tid >> 3;
            int k8 = tid & 7;
            union U { float4 f4; __half2 h2[4]; } u;
            for (int r = 0; r < 2; r++) {
                int n = n_l + r * 32;
                int row = nb + n;
                u.f4 = make_float4(0.f, 0.f, 0.f, 0.f);
                if (row < NN) u.f4 = ((const float4*)(hin + (size_t)row * HD))[k8];
                int g = n >> 2, nl2 = n & 3;
#pragma unroll
                for (int j = 0; j < 4; j++) {
                    float2 p = __half22float2(u.h2[j]);
                    int k = k8 * 8 + 2 * j;
                    int gp = g ^ (k & 15);
                    xS[k * 64 + gp * 4 + nl2] = p.x;
                    int k2 = k + 1;
                    int gp2 = g ^ (k2 & 15);
                    xS[k2 * 64 + gp2 * 4 + nl2] = p.y;
                }
            }
        }
        __syncthreads();
        float acc[4][4];
#pragma unroll
        for (int i = 0; i < 4; i++)
#pragma unroll
            for (int j = 0; j < 4; j++) acc[i][j] = 0.0f;
#pragma unroll 4
        for (int k = 0; k < HD; k++) {
            int gp = tn ^ (k & 15);
            float4 xv = *(const float4*)&xS[k * 64 + gp * 4];
            float4 wv = *(const float4*)&wS[k * 64 + f0];
            acc[0][0] = fmaf(xv.x, wv.x, acc[0][0]); acc[0][1] = fmaf(xv.x, wv.y, acc[0][1]);
            acc[0][2] = fmaf(xv.x, wv.z, acc[0][2]); acc[0][3] = fmaf(xv.x, wv.w, acc[0][3]);
            acc[1][0] = fmaf(xv.y, wv.x, acc[1][0]); acc[1][1] = fmaf(xv.y, wv.y, acc[1][1]);
            acc[1][2] = fmaf(xv.y, wv.z, acc[1][2]); acc[1][3] = fmaf(xv.y, wv.w, acc[1][3]);
            acc[2][0] = fmaf(xv.z, wv.x, acc[2][0]); acc[2][1] = fmaf(xv.z, wv.y, acc[2][1]);
            acc[2][2] = fmaf(xv.z, wv.z, acc[2][2]); acc[2][3] = fmaf(xv.z, wv.w, acc[2][3]);
            acc[3][0] = fmaf(xv.w, wv.x, acc[3][0]); acc[3][1] = fmaf(xv.w, wv.y, acc[3][1]);
            acc[3][2] = fmaf(xv.w, wv.z, acc[3][2]); acc[3][3] = fmaf(xv.w, wv.w, acc[3][3]);
        }
        int n0 = nb + tn * 4;
#pragma unroll
        for (int i = 0; i < 4; i++) {
            int n = n0 + i;
            if (n < NN) {
                float dn = di[n];
                __half2 p0 = __floats2half2_rn(acc[i][0] * dn, acc[i][1] * dn);
                __half2 p1 = __floats2half2_rn(acc[i][2] * dn, acc[i][3] * dn);
                __half2* o = (__half2*)(hws + (size_t)n * HD + f0);
                o[0] = p0; o[1] = p1;
            }
        }
    }
}

// =====================================================================
// Gather core, TWO nodes per wave: 4 independent dwordx4 loads in flight
// per unrolled round. Out-of-range shuffle sources carry NN (zero row),
// so mismatched list lengths need no guards (uniform control flow).
// =====================================================================
__device__ __forceinline__ void gather_half2(const int* __restrict__ offs,
                                             const int* __restrict__ pdeg,
                                             const unsigned int* __restrict__ ssrc,
                                             const __half* __restrict__ hws,
                                             int node0, int node1, int lane, int fp, int rsub,
                                             float acc0[8], float acc1[8]) {
    int i0 = offs[node0], i1 = offs[node1];
    int rem0 = pdeg[node0], rem1 = pdeg[node1];
    union U { float4 f4; __half2 h2[4]; } u0, u1, v0, v1;
    __half2 ha[4], hb[4];
#pragma unroll
    for (int t = 0; t < 4; t++) { ha[t] = __floats2half2_rn(0.f, 0.f); hb[t] = ha[t]; }
    if (rsub == 0) {  // self terms, counted once
        u0.f4 = ((const float4*)(hws + (size_t)node0 * HD))[fp];
        u1.f4 = ((const float4*)(hws + (size_t)node1 * HD))[fp];
#pragma unroll
        for (int t = 0; t < 4; t++) { ha[t] = __hadd2(ha[t], u0.h2[t]); hb[t] = __hadd2(hb[t], u1.h2[t]); }
    }
    while (rem0 > 0 || rem1 > 0) {
        int c0 = rem0 < 64 ? rem0 : 64;   // multiples of 8
        int c1 = rem1 < 64 ? rem1 : 64;
        int sl0 = (lane < c0) ? (int)ssrc[i0 + lane] : NN;
        int sl1 = (lane < c1) ? (int)ssrc[i1 + lane] : NN;
        int cm = c0 > c1 ? c0 : c1;
        int j = 0;
        for (; j + 16 <= cm; j += 16) {
            int s0a = __shfl(sl0, j + rsub, 64);
            int s1a = __shfl(sl1, j + rsub, 64);
            int s0b = __shfl(sl0, j + 8 + rsub, 64);
            int s1b = __shfl(sl1, j + 8 + rsub, 64);
            u0.f4 = ((const float4*)(hws + (size_t)s0a * HD))[fp];
            u1.f4 = ((const float4*)(hws + (size_t)s1a * HD))[fp];
            v0.f4 = ((const float4*)(hws + (size_t)s0b * HD))[fp];
            v1.f4 = ((const float4*)(hws + (size_t)s1b * HD))[fp];
#pragma unroll
            for (int t = 0; t < 4; t++) {
                ha[t] = __hadd2(ha[t], u0.h2[t]); hb[t] = __hadd2(hb[t], u1.h2[t]);
                ha[t] = __hadd2(ha[t], v0.h2[t]); hb[t] = __hadd2(hb[t], v1.h2[t]);
            }
        }
        if (j < cm) {   // one remaining 8-round
            int s0a = __shfl(sl0, j + rsub, 64);
            int s1a = __shfl(sl1, j + rsub, 64);
            u0.f4 = ((const float4*)(hws + (size_t)s0a * HD))[fp];
            u1.f4 = ((const float4*)(hws + (size_t)s1a * HD))[fp];
#pragma unroll
            for (int t = 0; t < 4; t++) { ha[t] = __hadd2(ha[t], u0.h2[t]); hb[t] = __hadd2(hb[t], u1.h2[t]); }
        }
        i0 += c0; rem0 -= c0;
        i1 += c1; rem1 -= c1;
    }
#pragma unroll
    for (int t = 0; t < 4; t++) {
        float2 p = __half22float2(ha[t]);
        acc0[2 * t] = p.x; acc0[2 * t + 1] = p.y;
        float2 q = __half22float2(hb[t]);
        acc1[2 * t] = q.x; acc1[2 * t + 1] = q.y;
    }
#pragma unroll
    for (int t = 0; t < 8; t++) {
        acc0[t] += __shfl_xor(acc0[t], 8, 64);
        acc0[t] += __shfl_xor(acc0[t], 16, 64);
        acc0[t] += __shfl_xor(acc0[t], 32, 64);
        acc1[t] += __shfl_xor(acc1[t], 8, 64);
        acc1[t] += __shfl_xor(acc1[t], 16, 64);
        acc1[t] += __shfl_xor(acc1[t], 32, 64);
    }
}

// LN over the 8-features-per-lane layout; returns relu'd y[8].
__device__ __forceinline__ void ln8(float v[8], int fp,
                                    const float* __restrict__ g,
                                    const float* __restrict__ bb,
                                    float y[8]) {
    float su = 0.0f;
#pragma unroll
    for (int t = 0; t < 8; t++) su += v[t];
    su += __shfl_xor(su, 1, 64); su += __shfl_xor(su, 2, 64); su += __shfl_xor(su, 4, 64);
    float mu = su * (1.0f / HD);
    float q = 0.0f;
#pragma unroll
    for (int t = 0; t < 8; t++) { float d = v[t] - mu; q += d * d; }
    q += __shfl_xor(q, 1, 64); q += __shfl_xor(q, 2, 64); q += __shfl_xor(q, 4, 64);
    float rstd = rsqrtf(q * (1.0f / HD) + 1e-5f);
    float4 ga = ((const float4*)g)[fp * 2], gb = ((const float4*)g)[fp * 2 + 1];
    float4 ba = ((const float4*)bb)[fp * 2], bc = ((const float4*)bb)[fp * 2 + 1];
    float gv[8] = {ga.x, ga.y, ga.z, ga.w, gb.x, gb.y, gb.z, gb.w};
    float bv[8] = {ba.x, ba.y, ba.z, ba.w, bc.x, bc.y, bc.z, bc.w};
#pragma unroll
    for (int t = 0; t < 8; t++) y[t] = fmaxf((v[t] - mu) * rstd * gv[t] + bv[t], 0.0f);
}

// ---------------- layer-1 gather (2 nodes/wave) + bias + LN + ReLU -> h1 fp16 ----------------
__global__ __launch_bounds__(256) void gather_ln(const int* __restrict__ offs,
                                                 const int* __restrict__ pdeg,
                                                 const unsigned int* __restrict__ ssrc,
                                                 const float* __restrict__ di,
                                                 const __half* __restrict__ hws,
                                                 const float* __restrict__ cb,
                                                 const float* __restrict__ g,
                                                 const float* __restrict__ bb,
                                                 __half* __restrict__ out) {
    int wv = threadIdx.x >> 6;
    int lane = threadIdx.x & 63;
    int fp = lane & 7, rsub = lane >> 3;
    int node0 = blockIdx.x * 8 + wv * 2;   // NN % 8 == 0
    int node1 = node0 + 1;
    float acc0[8], acc1[8];
    gather_half2(offs, pdeg, ssrc, hws, node0, node1, lane, fp, rsub, acc0, acc1);
    float4 ca = ((const float4*)cb)[fp * 2], cc = ((const float4*)cb)[fp * 2 + 1];
    float cv[8] = {ca.x, ca.y, ca.z, ca.w, cc.x, cc.y, cc.z, cc.w};
    float dn0 = di[node0], dn1 = di[node1];
    float v0[8], v1[8], y0[8], y1[8];
#pragma unroll
    for (int t = 0; t < 8; t++) { v0[t] = acc0[t] * dn0 + cv[t]; v1[t] = acc1[t] * dn1 + cv[t]; }
    ln8(v0, fp, g, bb, y0);
    ln8(v1, fp, g, bb, y1);
    if (rsub == 0) {
        union U { float4 f4; __half2 h2[4]; } u;
#pragma unroll
        for (int t = 0; t < 4; t++) u.h2[t] = __floats2half2_rn(y0[2 * t], y0[2 * t + 1]);
        ((float4*)(out + (size_t)node0 * HD))[fp] = u.f4;
#pragma unroll
        for (int t = 0; t < 4; t++) u.h2[t] = __floats2half2_rn(y1[2 * t], y1[2 * t + 1]);
        ((float4*)(out + (size_t)node1 * HD))[fp] = u.f4;
    }
}

// ---------------- layer-2 gather (2 nodes/wave) + LN + ReLU + skip + pooled scatter ----------------
__global__ __launch_bounds__(256) void gather_ln_pool(const int* __restrict__ offs,
                                                      const int* __restrict__ pdeg,
                                                      const unsigned int* __restrict__ ssrc,
                                                      const float* __restrict__ di,
                                                      const __half* __restrict__ hws,
                                                      const float* __restrict__ cb,
                                                      const float* __restrict__ g,
                                                      const float* __restrict__ bb,
                                                      const __half* __restrict__ h1,
                                                      const int* __restrict__ batch,
                                                      float* __restrict__ readout) {
    __shared__ float ls[8][HD];
    __shared__ int lb[8];
    int wv = threadIdx.x >> 6;
    int lane = threadIdx.x & 63;
    int fp = lane & 7, rsub = lane >> 3;
    int node0 = blockIdx.x * 8 + wv * 2;
    int node1 = node0 + 1;
    float acc0[8], acc1[8];
    gather_half2(offs, pdeg, ssrc, hws, node0, node1, lane, fp, rsub, acc0, acc1);
    float4 ca = ((const float4*)cb)[fp * 2], cc = ((const float4*)cb)[fp * 2 + 1];
    float cv[8] = {ca.x, ca.y, ca.z, ca.w, cc.x, cc.y, cc.z, cc.w};
    float dn0 = di[node0], dn1 = di[node1];
    float v0[8], v1[8], y0[8], y1[8];
#pragma unroll
    for (int t = 0; t < 8; t++) { v0[t] = acc0[t] * dn0 + cv[t]; v1[t] = acc1[t] * dn1 + cv[t]; }
    ln8(v0, fp, g, bb, y0);
    ln8(v1, fp, g, bb, y1);
    if (rsub == 0) {
        union U { float4 f4; __half2 h2[4]; } u;
        u.f4 = ((const float4*)(h1 + (size_t)node0 * HD))[fp];
        float* lr0 = &ls[wv * 2][fp * 8];
#pragma unroll
        for (int t = 0; t < 4; t++) {
            float2 p = __half22float2(u.h2[t]);
            lr0[2 * t] = y0[2 * t] + p.x;
            lr0[2 * t + 1] = y0[2 * t + 1] + p.y;
        }
        u.f4 = ((const float4*)(h1 + (size_t)node1 * HD))[fp];
        float* lr1 = &ls[wv * 2 + 1][fp * 8];
#pragma unroll
        for (int t = 0; t < 4; t++) {
            float2 p = __half22float2(u.h2[t]);
            lr1[2 * t] = y1[2 * t] + p.x;
            lr1[2 * t + 1] = y1[2 * t + 1] + p.y;
        }
    }
    if (lane == 0) { lb[wv * 2] = batch[node0]; lb[wv * 2 + 1] = batch[node1]; }
    __syncthreads();
    int f = lane;
    bool same8 = (lb[0] == lb[7]);   // batch sorted -> ends equal => all equal
    if (same8) {
        if (wv == 0) {
            float s = 0.0f;
#pragma unroll
            for (int r = 0; r < 8; r++) s += ls[r][f];
            atomicAdd(&readout[(size_t)lb[0] * HD + f], s);
        }
    } else {
        int r0 = wv * 2, r1 = r0 + 1;
        if (lb[r0] == lb[r1]) {
            atomicAdd(&readout[(size_t)lb[r0] * HD + f], ls[r0][f] + ls[r1][f]);
        } else {
            atomicAdd(&readout[(size_t)lb[r0] * HD + f], ls[r0][f]);
            atomicAdd(&readout[(size_t)lb[r1] * HD + f], ls[r1][f]);
        }
    }
}

// ---------------- final: out = readout @ post_w + post_b  [G,64]@[64,40] ----------------
__global__ __launch_bounds__(256) void out_gemm(const float* __restrict__ r,
                                                const float* __restrict__ w,
                                                const float* __restrict__ b,
                                                float* __restrict__ out) {
    __shared__ float lw[HD * CO];
    for (int i = threadIdx.x; i < HD * CO; i += 256) lw[i] = w[i];
    __syncthreads();
    int grp = blockIdx.x * 4 + (threadIdx.x >> 6);
    int c = threadIdx.x & 63;
    if (grp >= NG || c >= CO) return;
    const float* rr = r + (size_t)grp * HD;
    float acc = b[c];
#pragma unroll 8
    for (int k = 0; k < HD; k++) acc = fmaf(rr[k], lw[k * CO + c], acc);
    out[(size_t)grp * CO + c] = acc;
}

extern "C" void kernel_launch(void* const* d_in, const int* in_sizes, int n_in,
                              void* d_out, int out_size, void* d_ws, size_t ws_size,
                              hipStream_t stream) {
    const float* x      = (const float*)d_in[0];
    const int*   ei     = (const int*)d_in[1];
    const int*   batch  = (const int*)d_in[2];
    const float* pre_w  = (const float*)d_in[3];
    const float* pre_b  = (const float*)d_in[4];
    const float* c1_w   = (const float*)d_in[5];
    const float* c1_b   = (const float*)d_in[6];
    const float* n1_g   = (const float*)d_in[7];
    const float* n1_b   = (const float*)d_in[8];
    const float* c2_w   = (const float*)d_in[9];
    const float* c2_b   = (const float*)d_in[10];
    const float* n2_g   = (const float*)d_in[11];
    const float* n2_b   = (const float*)d_in[12];
    const float* post_w = (const float*)d_in[13];
    const float* post_b = (const float*)d_in[14];

    const int* src = ei;
    const int* dst = ei + NE;

    char* p = (char*)d_ws;
    int*          ccur    = (int*)p;          p += (size_t)NBUK * 16 * 4;
    int*          offs    = (int*)p;          p += (size_t)NN * 4;
    int*          degn    = (int*)p;          p += (size_t)NN * 4;
    float*        di      = (float*)p;        p += (size_t)NN * 4;
    float*        weff    = (float*)p;        p += (size_t)FIN * HD * 4;
    float*        beff    = (float*)p;        p += 256;
    unsigned int* tmp     = (unsigned int*)p; p += (size_t)NBUK * BCAP * 4;
    unsigned int* ssrc    = (unsigned int*)p; p += (size_t)NBUK * PCAP * 4;
    float*        readout = (float*)p;        p += (size_t)NG * HD * 4;
    __half*       hws     = (__half*)p;       p += (size_t)(NN + 8) * HD * 2;  // +dummy row
    __half*       h1      = (__half*)p;       p += (size_t)NN * HD * 2;

    // setup: cursors, readout zero, dummy hws row zero  (NG*HD = 131072 -> 512 blocks)
    setup_kernel<<<(NG * HD + 255) / 256, 256, 0, stream>>>(ccur, readout,
                                                            (unsigned int*)(hws + (size_t)NN * HD));

    // hierarchical CSR build
    scatter_binned<<<NSCAT, 256, 0, stream>>>(src, dst, ccur, tmp);
    bucket_sort<<<NBUK, 256, 0, stream>>>(ccur, tmp, ssrc, offs, degn, di);

    // Folded pre-MLP weights (one-shot; R12 showed fusing into gemm1 costs 768x redundant work)
    weff_kernel<<<33, 256, 0, stream>>>(pre_w, pre_b, c1_w, weff, beff);

    // layer 1
    gemm1_tiled<<<768, 256, 0, stream>>>(x, weff, beff, di, hws);
    gather_ln<<<NN / 8, 256, 0, stream>>>(offs, degn, ssrc, di, hws, c1_b, n1_g, n1_b, h1);

    // layer 2
    conv_gemm_tiled<<<1280, 256, 0, stream>>>(h1, c2_w, di, hws);
    gather_ln_pool<<<NN / 8, 256, 0, stream>>>(offs, degn, ssrc, di, hws, c2_b, n2_g, n2_b, h1, batch, readout);

    out_gemm<<<(NG + 3) / 4, 256, 0, stream>>>(readout, post_w, post_b, (float*)d_out);
}

// Round 15
// 302.313 us; speedup vs baseline: 1.2203x; 1.0000x over previous
//
#include <hip/hip_runtime.h>
#include <hip/hip_fp16.h>

#define NN 100000
#define NE 1600000
#define FIN 128
#define HD 64
#define CO 40
#define NG 2048
#define NSB 196           // super-buckets of 512 nodes: ceil(100000/512)
#define SCAP 9216         // super-bucket capacity (mean 8163, +11 sigma)
#define GCAP 13312        // padded ssrc capacity per group (SCAP + 512*7 pad)
#define CHUNK 4096        // edges per scatter block
#define NSCAT ((NE + CHUNK - 1) / CHUNK)   // 391

// ---------------- setup: cursors + zero readout + zero dummy hws row ----------------
__global__ __launch_bounds__(256) void setup_kernel(int* __restrict__ scur,
                                                    float* __restrict__ readout,
                                                    unsigned int* __restrict__ dummy) {
    int gid = blockIdx.x * 256 + threadIdx.x;
    if (gid < NG * HD) readout[gid] = 0.0f;
    if (gid < NSB) scur[gid * 16] = gid * SCAP;
    if (gid < HD / 2) dummy[gid] = 0u;   // 64 halves = 32 uints
}

// =====================================================================
// P1: binned scatter into 196 super-buckets (512 nodes each).
// Block-private ranges avg ~21 edges = 84 B -> line-dense writes.
// =====================================================================
__global__ __launch_bounds__(256) void scatter_super(const int* __restrict__ src,
                                                     const int* __restrict__ dst,
                                                     int* __restrict__ scur,
                                                     unsigned int* __restrict__ stmp) {
    __shared__ int hist[NSB];
    __shared__ int gbase[NSB];
    int tid = threadIdx.x;
    int e0 = blockIdx.x * CHUNK;
    int e1 = e0 + CHUNK; if (e1 > NE) e1 = NE;
    if (tid < NSB) hist[tid] = 0;
    __syncthreads();
    for (int e = e0 + tid; e < e1; e += 256) atomicAdd(&hist[dst[e] >> 9], 1);
    __syncthreads();
    if (tid < NSB) {
        int c = hist[tid];
        gbase[tid] = (c > 0) ? atomicAdd(&scur[tid * 16], c) : 0;
        hist[tid] = 0;
    }
    __syncthreads();
    for (int e = e0 + tid; e < e1; e += 256) {
        int d = dst[e];
        int s = src[e];
        int b = d >> 9;
        int p = atomicAdd(&hist[b], 1);
        stmp[gbase[b] + p] = ((unsigned int)(d & 511) << 17) | (unsigned int)s;
    }
}

// =====================================================================
// P2: per-super-bucket counting sort (512 node bins) -> padded ssrc,
// offs/degn/di. Writes are cursor-local to ONE block: zero global
// atomics, fully single-writer line assembly. Pads = dummy src NN.
// =====================================================================
__global__ __launch_bounds__(256) void group_sort(const int* __restrict__ scur,
                                                  const unsigned int* __restrict__ stmp,
                                                  unsigned int* __restrict__ ssrc,
                                                  int* __restrict__ offs,
                                                  int* __restrict__ degn,
                                                  float* __restrict__ di) {
    __shared__ int lh[512];
    __shared__ int lex[512];
    __shared__ int lcur[512];
    __shared__ int spair[256];
    int g = blockIdx.x;
    int tid = threadIdx.x;
    int base = g * SCAP;
    int cnt = scur[g * 16] - base;
    lh[tid] = 0; lh[tid + 256] = 0;
    __syncthreads();
    for (int i = tid; i < cnt; i += 256) atomicAdd(&lh[stmp[base + i] >> 17], 1);
    __syncthreads();
    int h0 = lh[2 * tid], h1 = lh[2 * tid + 1];
    int pd0 = (h0 + 7) & ~7, pd1 = (h1 + 7) & ~7;
    spair[tid] = pd0 + pd1;
    __syncthreads();
    for (int off = 1; off < 256; off <<= 1) {
        int v = (tid >= off) ? spair[tid - off] : 0;
        __syncthreads();
        spair[tid] += v;
        __syncthreads();
    }
    int pairExcl = spair[tid] - (pd0 + pd1);
    int e0 = pairExcl, e1 = pairExcl + pd0;
    lex[2 * tid] = e0; lex[2 * tid + 1] = e1;
    lcur[2 * tid] = e0; lcur[2 * tid + 1] = e1;
    int node0 = g * 512 + 2 * tid, node1 = node0 + 1;
    if (node0 < NN) { offs[node0] = g * GCAP + e0; degn[node0] = pd0; di[node0] = rsqrtf((float)h0 + 1.0f); }
    if (node1 < NN) { offs[node1] = g * GCAP + e1; degn[node1] = pd1; di[node1] = rsqrtf((float)h1 + 1.0f); }
    __syncthreads();
    // write pad entries (<=7 per node, disjoint from scatter positions)
    {
        size_t gb = (size_t)g * GCAP;
        for (int q = h0; q < pd0; q++) ssrc[gb + e0 + q] = (unsigned int)NN;
        for (int q = h1; q < pd1; q++) ssrc[gb + e1 + q] = (unsigned int)NN;
    }
    // scatter edges to their node slots (cursor-local, no global atomics)
    for (int i = tid; i < cnt; i += 256) {
        unsigned int u = stmp[base + i];
        int dl = (int)(u >> 17);
        int pos = atomicAdd(&lcur[dl], 1);
        ssrc[(size_t)g * GCAP + pos] = u & 0x1FFFFu;
    }
}

// ---------------- W_eff = pre_w @ c1_w ; b_eff = pre_b @ c1_w (one-shot) ----------------
__global__ __launch_bounds__(256) void weff_kernel(const float* __restrict__ pre_w,
                                                   const float* __restrict__ pre_b,
                                                   const float* __restrict__ c1_w,
                                                   float* __restrict__ weff,
                                                   float* __restrict__ beff) {
    if (blockIdx.x < 32) {
        int o = blockIdx.x * 256 + threadIdx.x;
        int r = o >> 6, c = o & 63;
        float acc = 0.0f;
#pragma unroll 8
        for (int k = 0; k < HD; k++) acc = fmaf(pre_w[r * HD + k], c1_w[k * HD + c], acc);
        weff[o] = acc;
    } else {
        int c = threadIdx.x;
        if (c < HD) {
            float acc = 0.0f;
#pragma unroll 8
            for (int k = 0; k < HD; k++) acc = fmaf(pre_b[k], c1_w[k * HD + c], acc);
            beff[c] = acc;
        }
    }
}

// =====================================================================
// Tiled GEMM 1: hws = half((x @ W_eff + b_eff) * di)   [N,128]@[128,64]
// =====================================================================
__global__ __launch_bounds__(256) void gemm1_tiled(const float* __restrict__ x,
                                                   const float* __restrict__ w,
                                                   const float* __restrict__ b,
                                                   const float* __restrict__ di,
                                                   __half* __restrict__ hws) {
    __shared__ float wS[FIN * HD];   // 32 KB
    __shared__ float xS[64 * 64];    // 16 KB (one K-half)
    int tid = threadIdx.x;
    for (int i = tid; i < FIN * HD; i += 256) wS[i] = w[i];
    int tn = tid & 15, tf = tid >> 4;
    int f0 = tf * 4;
    float4 bv = ((const float4*)b)[tf];
    int ntiles = (NN + 63) >> 6;
    for (int t = blockIdx.x; t < ntiles; t += gridDim.x) {
        int nb = t << 6;
        float acc[4][4];
#pragma unroll
        for (int i = 0; i < 4; i++)
#pragma unroll
            for (int j = 0; j < 4; j++) acc[i][j] = 0.0f;
        for (int kh = 0; kh < 2; kh++) {
            __syncthreads();
            {
                int n_l = tid >> 4;
                int k4l = tid & 15;
                for (int r = 0; r < 4; r++) {
                    int n = n_l + r * 16;
                    int row = nb + n;
                    float4 v = make_float4(0.f, 0.f, 0.f, 0.f);
                    if (row < NN) v = ((const float4*)(x + (size_t)row * FIN))[kh * 16 + k4l];
                    int g = n >> 2, nl2 = n & 3;
                    const float* vp = (const float*)&v;
#pragma unroll
                    for (int j = 0; j < 4; j++) {
                        int k = k4l * 4 + j;
                        int gp = g ^ (k & 15);
                        xS[k * 64 + gp * 4 + nl2] = vp[j];
                    }
                }
            }
            __syncthreads();
#pragma unroll 4
            for (int kl = 0; kl < 64; kl++) {
                int gp = tn ^ (kl & 15);
                float4 xv = *(const float4*)&xS[kl * 64 + gp * 4];
                float4 wv = *(const float4*)&wS[(kh * 64 + kl) * 64 + f0];
                acc[0][0] = fmaf(xv.x, wv.x, acc[0][0]); acc[0][1] = fmaf(xv.x, wv.y, acc[0][1]);
                acc[0][2] = fmaf(xv.x, wv.z, acc[0][2]); acc[0][3] = fmaf(xv.x, wv.w, acc[0][3]);
                acc[1][0] = fmaf(xv.y, wv.x, acc[1][0]); acc[1][1] = fmaf(xv.y, wv.y, acc[1][1]);
                acc[1][2] = fmaf(xv.y, wv.z, acc[1][2]); acc[1][3] = fmaf(xv.y, wv.w, acc[1][3]);
                acc[2][0] = fmaf(xv.z, wv.x, acc[2][0]); acc[2][1] = fmaf(xv.z, wv.y, acc[2][1]);
                acc[2][2] = fmaf(xv.z, wv.z, acc[2][2]); acc[2][3] = fmaf(xv.z, wv.w, acc[2][3]);
                acc[3][0] = fmaf(xv.w, wv.x, acc[3][0]); acc[3][1] = fmaf(xv.w, wv.y, acc[3][1]);
                acc[3][2] = fmaf(xv.w, wv.z, acc[3][2]); acc[3][3] = fmaf(xv.w, wv.w, acc[3][3]);
            }
        }
        int n0 = nb + tn * 4;
#pragma unroll
        for (int i = 0; i < 4; i++) {
            int n = n0 + i;
            if (n < NN) {
                float dn = di[n];
                __half2 p0 = __floats2half2_rn((acc[i][0] + bv.x) * dn, (acc[i][1] + bv.y) * dn);
                __half2 p1 = __floats2half2_rn((acc[i][2] + bv.z) * dn, (acc[i][3] + bv.w) * dn);
                __half2* o = (__half2*)(hws + (size_t)n * HD + f0);
                o[0] = p0; o[1] = p1;
            }
        }
    }
}

// =====================================================================
// Tiled GEMM 2: hws = half((h1 @ c2_w) * di)   [N,64]@[64,64], h1 fp16
// =====================================================================
__global__ __launch_bounds__(256) void conv_gemm_tiled(const __half* __restrict__ hin,
                                                       const float* __restrict__ w,
                                                       const float* __restrict__ di,
                                                       __half* __restrict__ hws) {
    __shared__ float wS[HD * HD];
    __shared__ float xS[64 * HD];
    int tid = threadIdx.x;
    for (int i = tid; i < HD * HD; i += 256) wS[i] = w[i];
    int tn = tid & 15, tf = tid >> 4;
    int f0 = tf * 4;
    int ntiles = (NN + 63) >> 6;
    for (int t = blockIdx.x; t < ntiles; t += gridDim.x) {
        int nb = t << 6;
        __syncthreads();
        {
            int n_l = tid >> 3;
            int k8 = tid & 7;
            union U { float4 f4; __half2 h2[4]; } u;
            for (int r = 0; r < 2; r++) {
                int n = n_l + r * 32;
                int row = nb + n;
                u.f4 = make_float4(0.f, 0.f, 0.f, 0.f);
                if (row < NN) u.f4 = ((const float4*)(hin + (size_t)row * HD))[k8];
                int g = n >> 2, nl2 = n & 3;
#pragma unroll
                for (int j = 0; j < 4; j++) {
                    float2 p = __half22float2(u.h2[j]);
                    int k = k8 * 8 + 2 * j;
                    int gp = g ^ (k & 15);
                    xS[k * 64 + gp * 4 + nl2] = p.x;
                    int k2 = k + 1;
                    int gp2 = g ^ (k2 & 15);
                    xS[k2 * 64 + gp2 * 4 + nl2] = p.y;
                }
            }
        }
        __syncthreads();
        float acc[4][4];
#pragma unroll
        for (int i = 0; i < 4; i++)
#pragma unroll
            for (int j = 0; j < 4; j++) acc[i][j] = 0.0f;
#pragma unroll 4
        for (int k = 0; k < HD; k++) {
            int gp = tn ^ (k & 15);
            float4 xv = *(const float4*)&xS[k * 64 + gp * 4];
            float4 wv = *(const float4*)&wS[k * 64 + f0];
            acc[0][0] = fmaf(xv.x, wv.x, acc[0][0]); acc[0][1] = fmaf(xv.x, wv.y, acc[0][1]);
            acc[0][2] = fmaf(xv.x, wv.z, acc[0][2]); acc[0][3] = fmaf(xv.x, wv.w, acc[0][3]);
            acc[1][0] = fmaf(xv.y, wv.x, acc[1][0]); acc[1][1] = fmaf(xv.y, wv.y, acc[1][1]);
            acc[1][2] = fmaf(xv.y, wv.z, acc[1][2]); acc[1][3] = fmaf(xv.y, wv.w, acc[1][3]);
            acc[2][0] = fmaf(xv.z, wv.x, acc[2][0]); acc[2][1] = fmaf(xv.z, wv.y, acc[2][1]);
            acc[2][2] = fmaf(xv.z, wv.z, acc[2][2]); acc[2][3] = fmaf(xv.z, wv.w, acc[2][3]);
            acc[3][0] = fmaf(xv.w, wv.x, acc[3][0]); acc[3][1] = fmaf(xv.w, wv.y, acc[3][1]);
            acc[3][2] = fmaf(xv.w, wv.z, acc[3][2]); acc[3][3] = fmaf(xv.w, wv.w, acc[3][3]);
        }
        int n0 = nb + tn * 4;
#pragma unroll
        for (int i = 0; i < 4; i++) {
            int n = n0 + i;
            if (n < NN) {
                float dn = di[n];
                __half2 p0 = __floats2half2_rn(acc[i][0] * dn, acc[i][1] * dn);
                __half2 p1 = __floats2half2_rn(acc[i][2] * dn, acc[i][3] * dn);
                __half2* o = (__half2*)(hws + (size_t)n * HD + f0);
                o[0] = p0; o[1] = p1;
            }
        }
    }
}

// =====================================================================
// Gather core, TWO nodes per wave: 4 independent dwordx4 loads in flight
// per unrolled round. Out-of-range shuffle sources carry NN (zero row).
// =====================================================================
__device__ __forceinline__ void gather_half2(const int* __restrict__ offs,
                                             const int* __restrict__ pdeg,
                                             const unsigned int* __restrict__ ssrc,
                                             const __half* __restrict__ hws,
                                             int node0, int node1, int lane, int fp, int rsub,
                                             float acc0[8], float acc1[8]) {
    int i0 = offs[node0], i1 = offs[node1];
    int rem0 = pdeg[node0], rem1 = pdeg[node1];
    union U { float4 f4; __half2 h2[4]; } u0, u1, v0, v1;
    __half2 ha[4], hb[4];
#pragma unroll
    for (int t = 0; t < 4; t++) { ha[t] = __floats2half2_rn(0.f, 0.f); hb[t] = ha[t]; }
    if (rsub == 0) {
        u0.f4 = ((const float4*)(hws + (size_t)node0 * HD))[fp];
        u1.f4 = ((const float4*)(hws + (size_t)node1 * HD))[fp];
#pragma unroll
        for (int t = 0; t < 4; t++) { ha[t] = __hadd2(ha[t], u0.h2[t]); hb[t] = __hadd2(hb[t], u1.h2[t]); }
    }
    while (rem0 > 0 || rem1 > 0) {
        int c0 = rem0 < 64 ? rem0 : 64;
        int c1 = rem1 < 64 ? rem1 : 64;
        int sl0 = (lane < c0) ? (int)ssrc[i0 + lane] : NN;
        int sl1 = (lane < c1) ? (int)ssrc[i1 + lane] : NN;
        int cm = c0 > c1 ? c0 : c1;
        int j = 0;
        for (; j + 16 <= cm; j += 16) {
            int s0a = __shfl(sl0, j + rsub, 64);
            int s1a = __shfl(sl1, j + rsub, 64);
            int s0b = __shfl(sl0, j + 8 + rsub, 64);
            int s1b = __shfl(sl1, j + 8 + rsub, 64);
            u0.f4 = ((const float4*)(hws + (size_t)s0a * HD))[fp];
            u1.f4 = ((const float4*)(hws + (size_t)s1a * HD))[fp];
            v0.f4 = ((const float4*)(hws + (size_t)s0b * HD))[fp];
            v1.f4 = ((const float4*)(hws + (size_t)s1b * HD))[fp];
#pragma unroll
            for (int t = 0; t < 4; t++) {
                ha[t] = __hadd2(ha[t], u0.h2[t]); hb[t] = __hadd2(hb[t], u1.h2[t]);
                ha[t] = __hadd2(ha[t], v0.h2[t]); hb[t] = __hadd2(hb[t], v1.h2[t]);
            }
        }
        if (j < cm) {
            int s0a = __shfl(sl0, j + rsub, 64);
            int s1a = __shfl(sl1, j + rsub, 64);
            u0.f4 = ((const float4*)(hws + (size_t)s0a * HD))[fp];
            u1.f4 = ((const float4*)(hws + (size_t)s1a * HD))[fp];
#pragma unroll
            for (int t = 0; t < 4; t++) { ha[t] = __hadd2(ha[t], u0.h2[t]); hb[t] = __hadd2(hb[t], u1.h2[t]); }
        }
        i0 += c0; rem0 -= c0;
        i1 += c1; rem1 -= c1;
    }
#pragma unroll
    for (int t = 0; t < 4; t++) {
        float2 p = __half22float2(ha[t]);
        acc0[2 * t] = p.x; acc0[2 * t + 1] = p.y;
        float2 q = __half22float2(hb[t]);
        acc1[2 * t] = q.x; acc1[2 * t + 1] = q.y;
    }
#pragma unroll
    for (int t = 0; t < 8; t++) {
        acc0[t] += __shfl_xor(acc0[t], 8, 64);
        acc0[t] += __shfl_xor(acc0[t], 16, 64);
        acc0[t] += __shfl_xor(acc0[t], 32, 64);
        acc1[t] += __shfl_xor(acc1[t], 8, 64);
        acc1[t] += __shfl_xor(acc1[t], 16, 64);
        acc1[t] += __shfl_xor(acc1[t], 32, 64);
    }
}

// LN over the 8-features-per-lane layout; returns relu'd y[8].
__device__ __forceinline__ void ln8(float v[8], int fp,
                                    const float* __restrict__ g,
                                    const float* __restrict__ bb,
                                    float y[8]) {
    float su = 0.0f;
#pragma unroll
    for (int t = 0; t < 8; t++) su += v[t];
    su += __shfl_xor(su, 1, 64); su += __shfl_xor(su, 2, 64); su += __shfl_xor(su, 4, 64);
    float mu = su * (1.0f / HD);
    float q = 0.0f;
#pragma unroll
    for (int t = 0; t < 8; t++) { float d = v[t] - mu; q += d * d; }
    q += __shfl_xor(q, 1, 64); q += __shfl_xor(q, 2, 64); q += __shfl_xor(q, 4, 64);
    float rstd = rsqrtf(q * (1.0f / HD) + 1e-5f);
    float4 ga = ((const float4*)g)[fp * 2], gb = ((const float4*)g)[fp * 2 + 1];
    float4 ba = ((const float4*)bb)[fp * 2], bc = ((const float4*)bb)[fp * 2 + 1];
    float gv[8] = {ga.x, ga.y, ga.z, ga.w, gb.x, gb.y, gb.z, gb.w};
    float bv[8] = {ba.x, ba.y, ba.z, ba.w, bc.x, bc.y, bc.z, bc.w};
#pragma unroll
    for (int t = 0; t < 8; t++) y[t] = fmaxf((v[t] - mu) * rstd * gv[t] + bv[t], 0.0f);
}

// ---------------- layer-1 gather (2 nodes/wave) + bias + LN + ReLU -> h1 fp16 ----------------
__global__ __launch_bounds__(256) void gather_ln(const int* __restrict__ offs,
                                                 const int* __restrict__ pdeg,
                                                 const unsigned int* __restrict__ ssrc,
                                                 const float* __restrict__ di,
                                                 const __half* __restrict__ hws,
                                                 const float* __restrict__ cb,
                                                 const float* __restrict__ g,
                                                 const float* __restrict__ bb,
                                                 __half* __restrict__ out) {
    int wv = threadIdx.x >> 6;
    int lane = threadIdx.x & 63;
    int fp = lane & 7, rsub = lane >> 3;
    int node0 = blockIdx.x * 8 + wv * 2;   // NN % 8 == 0
    int node1 = node0 + 1;
    float acc0[8], acc1[8];
    gather_half2(offs, pdeg, ssrc, hws, node0, node1, lane, fp, rsub, acc0, acc1);
    float4 ca = ((const float4*)cb)[fp * 2], cc = ((const float4*)cb)[fp * 2 + 1];
    float cv[8] = {ca.x, ca.y, ca.z, ca.w, cc.x, cc.y, cc.z, cc.w};
    float dn0 = di[node0], dn1 = di[node1];
    float v0[8], v1[8], y0[8], y1[8];
#pragma unroll
    for (int t = 0; t < 8; t++) { v0[t] = acc0[t] * dn0 + cv[t]; v1[t] = acc1[t] * dn1 + cv[t]; }
    ln8(v0, fp, g, bb, y0);
    ln8(v1, fp, g, bb, y1);
    if (rsub == 0) {
        union U { float4 f4; __half2 h2[4]; } u;
#pragma unroll
        for (int t = 0; t < 4; t++) u.h2[t] = __floats2half2_rn(y0[2 * t], y0[2 * t + 1]);
        ((float4*)(out + (size_t)node0 * HD))[fp] = u.f4;
#pragma unroll
        for (int t = 0; t < 4; t++) u.h2[t] = __floats2half2_rn(y1[2 * t], y1[2 * t + 1]);
        ((float4*)(out + (size_t)node1 * HD))[fp] = u.f4;
    }
}

// ---------------- layer-2 gather (2 nodes/wave) + LN + ReLU + skip + pooled scatter ----------------
__global__ __launch_bounds__(256) void gather_ln_pool(const int* __restrict__ offs,
                                                      const int* __restrict__ pdeg,
                                                      const unsigned int* __restrict__ ssrc,
                                                      const float* __restrict__ di,
                                                      const __half* __restrict__ hws,
                                                      const float* __restrict__ cb,
                                                      const float* __restrict__ g,
                                                      const float* __restrict__ bb,
                                                      const __half* __restrict__ h1,
                                                      const int* __restrict__ batch,
                                                      float* __restrict__ readout) {
    __shared__ float ls[8][HD];
    __shared__ int lb[8];
    int wv = threadIdx.x >> 6;
    int lane = threadIdx.x & 63;
    int fp = lane & 7, rsub = lane >> 3;
    int node0 = blockIdx.x * 8 + wv * 2;
    int node1 = node0 + 1;
    float acc0[8], acc1[8];
    gather_half2(offs, pdeg, ssrc, hws, node0, node1, lane, fp, rsub, acc0, acc1);
    float4 ca = ((const float4*)cb)[fp * 2], cc = ((const float4*)cb)[fp * 2 + 1];
    float cv[8] = {ca.x, ca.y, ca.z, ca.w, cc.x, cc.y, cc.z, cc.w};
    float dn0 = di[node0], dn1 = di[node1];
    float v0[8], v1[8], y0[8], y1[8];
#pragma unroll
    for (int t = 0; t < 8; t++) { v0[t] = acc0[t] * dn0 + cv[t]; v1[t] = acc1[t] * dn1 + cv[t]; }
    ln8(v0, fp, g, bb, y0);
    ln8(v1, fp, g, bb, y1);
    if (rsub == 0) {
        union U { float4 f4; __half2 h2[4]; } u;
        u.f4 = ((const float4*)(h1 + (size_t)node0 * HD))[fp];
        float* lr0 = &ls[wv * 2][fp * 8];
#pragma unroll
        for (int t = 0; t < 4; t++) {
            float2 p = __half22float2(u.h2[t]);
            lr0[2 * t] = y0[2 * t] + p.x;
            lr0[2 * t + 1] = y0[2 * t + 1] + p.y;
        }
        u.f4 = ((const float4*)(h1 + (size_t)node1 * HD))[fp];
        float* lr1 = &ls[wv * 2 + 1][fp * 8];
#pragma unroll
        for (int t = 0; t < 4; t++) {
            float2 p = __half22float2(u.h2[t]);
            lr1[2 * t] = y1[2 * t] + p.x;
            lr1[2 * t + 1] = y1[2 * t + 1] + p.y;
        }
    }
    if (lane == 0) { lb[wv * 2] = batch[node0]; lb[wv * 2 + 1] = batch[node1]; }
    __syncthreads();
    int f = lane;
    bool same8 = (lb[0] == lb[7]);   // batch sorted
    if (same8) {
        if (wv == 0) {
            float s = 0.0f;
#pragma unroll
            for (int r = 0; r < 8; r++) s += ls[r][f];
            atomicAdd(&readout[(size_t)lb[0] * HD + f], s);
        }
    } else {
        int r0 = wv * 2, r1 = r0 + 1;
        if (lb[r0] == lb[r1]) {
            atomicAdd(&readout[(size_t)lb[r0] * HD + f], ls[r0][f] + ls[r1][f]);
        } else {
            atomicAdd(&readout[(size_t)lb[r0] * HD + f], ls[r0][f]);
            atomicAdd(&readout[(size_t)lb[r1] * HD + f], ls[r1][f]);
        }
    }
}

// ---------------- final: out = readout @ post_w + post_b  [G,64]@[64,40] ----------------
__global__ __launch_bounds__(256) void out_gemm(const float* __restrict__ r,
                                                const float* __restrict__ w,
                                                const float* __restrict__ b,
                                                float* __restrict__ out) {
    __shared__ float lw[HD * CO];
    for (int i = threadIdx.x; i < HD * CO; i += 256) lw[i] = w[i];
    __syncthreads();
    int grp = blockIdx.x * 4 + (threadIdx.x >> 6);
    int c = threadIdx.x & 63;
    if (grp >= NG || c >= CO) return;
    const float* rr = r + (size_t)grp * HD;
    float acc = b[c];
#pragma unroll 8
    for (int k = 0; k < HD; k++) acc = fmaf(rr[k], lw[k * CO + c], acc);
    out[(size_t)grp * CO + c] = acc;
}

extern "C" void kernel_launch(void* const* d_in, const int* in_sizes, int n_in,
                              void* d_out, int out_size, void* d_ws, size_t ws_size,
                              hipStream_t stream) {
    const float* x      = (const float*)d_in[0];
    const int*   ei     = (const int*)d_in[1];
    const int*   batch  = (const int*)d_in[2];
    const float* pre_w  = (const float*)d_in[3];
    const float* pre_b  = (const float*)d_in[4];
    const float* c1_w   = (const float*)d_in[5];
    const float* c1_b   = (const float*)d_in[6];
    const float* n1_g   = (const float*)d_in[7];
    const float* n1_b   = (const float*)d_in[8];
    const float* c2_w   = (const float*)d_in[9];
    const float* c2_b   = (const float*)d_in[10];
    const float* n2_g   = (const float*)d_in[11];
    const float* n2_b   = (const float*)d_in[12];
    const float* post_w = (const float*)d_in[13];
    const float* post_b = (const float*)d_in[14];

    const int* src = ei;
    const int* dst = ei + NE;

    char* p = (char*)d_ws;
    int*          scur    = (int*)p;          p += (size_t)NSB * 16 * 4;
    int*          offs    = (int*)p;          p += (size_t)NN * 4;
    int*          degn    = (int*)p;          p += (size_t)NN * 4;
    float*        di      = (float*)p;        p += (size_t)NN * 4;
    float*        weff    = (float*)p;        p += (size_t)FIN * HD * 4;
    float*        beff    = (float*)p;        p += 256;
    unsigned int* stmp    = (unsigned int*)p; p += (size_t)NSB * SCAP * 4;
    unsigned int* ssrc    = (unsigned int*)p; p += (size_t)NSB * GCAP * 4;
    float*        readout = (float*)p;        p += (size_t)NG * HD * 4;
    __half*       hws     = (__half*)p;       p += (size_t)(NN + 8) * HD * 2;  // +dummy row
    __half*       h1      = (__half*)p;       p += (size_t)NN * HD * 2;

    // setup: cursors, readout zero, dummy hws row zero
    setup_kernel<<<(NG * HD + 255) / 256, 256, 0, stream>>>(scur, readout,
                                                            (unsigned int*)(hws + (size_t)NN * HD));

    // two-level CSR build: super-bucket scatter -> per-group counting sort
    scatter_super<<<NSCAT, 256, 0, stream>>>(src, dst, scur, stmp);
    group_sort<<<NSB, 256, 0, stream>>>(scur, stmp, ssrc, offs, degn, di);

    // Folded pre-MLP weights (one-shot; fusing into gemm1 costs 768x redundant work — R12)
    weff_kernel<<<33, 256, 0, stream>>>(pre_w, pre_b, c1_w, weff, beff);

    // layer 1
    gemm1_tiled<<<768, 256, 0, stream>>>(x, weff, beff, di, hws);
    gather_ln<<<NN / 8, 256, 0, stream>>>(offs, degn, ssrc, di, hws, c1_b, n1_g, n1_b, h1);

    // layer 2
    conv_gemm_tiled<<<1280, 256, 0, stream>>>(h1, c2_w, di, hws);
    gather_ln_pool<<<NN / 8, 256, 0, stream>>>(offs, degn, ssrc, di, hws, c2_b, n2_g, n2_b, h1, batch, readout);

    out_gemm<<<(NG + 3) / 4, 256, 0, stream>>>(readout, post_w, post_b, (float*)d_out);
}